// Round 12
// baseline (821.685 us; speedup 1.0000x reference)
//
#include <hip/hip_runtime.h>
#include <hip/hip_bf16.h>

typedef __hip_bfloat16 bf16;

#define NT 262144
#define ND 262144
#define EDT 2097152
#define ETT 1048576
#define NSLOT (2*NT)            // [0,NT)=d2t dst slots, [NT,2NT)=tt dst slots
#define NE_TOT (EDT+ETT)        // 3145728
#define NBKT 1024               // coarse buckets, bucket = slot>>9
#define SPB 512                 // slots per bucket
#define BCAP 3072               // per-bucket ebuf capacity (mean ~2048)
#define CH 8192                 // edges per phase-1 block (32KB stage)
#define NBLK1 (NE_TOT/CH)       // 384

// ---- dual-dtype load/store: isbf==1 -> bf16, else fp32 ----
__device__ __forceinline__ float ldf(const void* p, long i, int isbf){
    if (isbf) return __bfloat162float(((const bf16*)p)[i]);
    return ((const float*)p)[i];
}
__device__ __forceinline__ void stf(void* p, int i, float v, int isbf){
    if (isbf) ((bf16*)p)[i] = __float2bfloat16(v);
    else      ((float*)p)[i] = v;
}
__device__ __forceinline__ float fin(float x){
    return (x==x && x>-3e38f && x<3e38f) ? x : 0.f;
}
// ---- bf16x2 pack/unpack ----
__device__ __forceinline__ unsigned pk2(float a, float b){
    bf16 ha = __float2bfloat16(a), hb = __float2bfloat16(b);
    unsigned short ua = *(unsigned short*)&ha, ub = *(unsigned short*)&hb;
    return ((unsigned)ub<<16) | (unsigned)ua;
}
__device__ __forceinline__ float ulo(unsigned u){ return __uint_as_float(u<<16); }
__device__ __forceinline__ float uhi(unsigned u){ return __uint_as_float(u & 0xffff0000u); }

// score contribution of 8 packed channels (leaky_relu(x+xr)·att)
__device__ __forceinline__ float score8(uint4 u, const float* xr, const float* at){
    float s=0.f, m;
    m = ulo(u.x)+xr[0]; m = m>0.f?m:0.2f*m; s += m*at[0];
    m = uhi(u.x)+xr[1]; m = m>0.f?m:0.2f*m; s += m*at[1];
    m = ulo(u.y)+xr[2]; m = m>0.f?m:0.2f*m; s += m*at[2];
    m = uhi(u.y)+xr[3]; m = m>0.f?m:0.2f*m; s += m*at[3];
    m = ulo(u.z)+xr[4]; m = m>0.f?m:0.2f*m; s += m*at[4];
    m = uhi(u.z)+xr[5]; m = m>0.f?m:0.2f*m; s += m*at[5];
    m = ulo(u.w)+xr[6]; m = m>0.f?m:0.2f*m; s += m*at[6];
    m = uhi(u.w)+xr[7]; m = m>0.f?m:0.2f*m; s += m*at[7];
    return s;
}
__device__ __forceinline__ void acc8(uint4 u, float a, float* acc){
    acc[0] += a*ulo(u.x); acc[1] += a*uhi(u.x);
    acc[2] += a*ulo(u.y); acc[3] += a*uhi(u.y);
    acc[4] += a*ulo(u.z); acc[5] += a*uhi(u.z);
    acc[6] += a*ulo(u.w); acc[7] += a*uhi(u.w);
}

// ---- input dtype detection: low-16-bit exponent census (see R2 notes) ----
__global__ void detect_kernel(const unsigned* __restrict__ raw, int* __restrict__ flag){
    __shared__ int cnt;
    if (threadIdx.x==0) cnt = 0;
    __syncthreads();
    int c = 0;
    for (int i = threadIdx.x; i < 2048; i += 256){
        unsigned w = raw[i];
        unsigned e = (w >> 7) & 0xFFu;
        if (e >= 116u && e <= 134u) c++;
    }
    atomicAdd(&cnt, c);
    __syncthreads();
    if (threadIdx.x==0) *flag = (cnt > 1024) ? 1 : 0;
}

__global__ void init_cursors_kernel(int* __restrict__ bktCur){
    int i = blockIdx.x*256 + threadIdx.x;
    if (i < NBKT) bktCur[i] = i*BCAP;
}

// ---------------- task stem: x_tasks -> xt[NT,16], fused @tt_Wl -> xl_tt (bf16-packed) ----------------
__global__ __launch_bounds__(256) void stem_task_kernel(
    const void* __restrict__ x, const void* __restrict__ W, const void* __restrict__ bias,
    const void* __restrict__ lng, const void* __restrict__ lnb,
    const void* __restrict__ Wl_tt, float* __restrict__ xt, unsigned* __restrict__ xl_tt,
    const int* __restrict__ flag)
{
    int isbf = *flag;
    __shared__ float sW[192], sb[16], sg[16], sbt[16], sWl[512];
    int t = threadIdx.x;
    if (t < 192) sW[t] = ldf(W, t, isbf);
    if (t < 16){ sb[t]=ldf(bias,t,isbf); sg[t]=ldf(lng,t,isbf); sbt[t]=ldf(lnb,t,isbf); }
    sWl[t]     = ldf(Wl_tt, t,     isbf);
    sWl[t+256] = ldf(Wl_tt, t+256, isbf);
    __syncthreads();
    long i = blockIdx.x*256 + t;
    float f[12];
    #pragma unroll
    for (int k=0;k<12;k++) f[k] = ldf(x, i*12+k, isbf);
    float h[16];
    #pragma unroll
    for (int c=0;c<16;c++){
        float a = sb[c];
        #pragma unroll
        for (int k=0;k<12;k++) a += f[k]*sW[k*16+c];
        h[c]=a;
    }
    float mu=0.f;
    #pragma unroll
    for (int c=0;c<16;c++) mu += h[c];
    mu *= (1.f/16.f);
    float var=0.f;
    #pragma unroll
    for (int c=0;c<16;c++){ float d=h[c]-mu; var += d*d; }
    var *= (1.f/16.f);
    float inv = rsqrtf(var + 1e-5f);
    float v[16];
    #pragma unroll
    for (int c=0;c<16;c++){
        float y = sg[c]*(h[c]-mu)*inv + sbt[c];
        v[c] = fin((y>0.f) ? y : 0.01f*y);
    }
    float4* xp = (float4*)(xt + i*16);
    #pragma unroll
    for (int q=0;q<4;q++) xp[q] = make_float4(v[q*4],v[q*4+1],v[q*4+2],v[q*4+3]);
    float o[32];
    #pragma unroll
    for (int c=0;c<32;c++) o[c]=0.f;
    #pragma unroll
    for (int k=0;k<16;k++){
        float xv=v[k];
        #pragma unroll
        for (int c=0;c<32;c++) o[c] += xv*sWl[k*32+c];
    }
    #pragma unroll
    for (int c=0;c<32;c++) o[c] = fin(o[c]);
    uint4* op = (uint4*)(xl_tt + i*16);
    #pragma unroll
    for (int q=0;q<4;q++)
        op[q] = make_uint4(pk2(o[q*8],o[q*8+1]), pk2(o[q*8+2],o[q*8+3]),
                           pk2(o[q*8+4],o[q*8+5]), pk2(o[q*8+6],o[q*8+7]));
}

// data stem fused with @dt_Wl -> xl_dt (bf16-packed)
__global__ __launch_bounds__(256) void stem_data_transform_kernel(
    const void* __restrict__ x, const void* __restrict__ W, const void* __restrict__ bias,
    const void* __restrict__ lng, const void* __restrict__ lnb,
    const void* __restrict__ Wl, unsigned* __restrict__ xl,
    const int* __restrict__ flag)
{
    int isbf = *flag;
    __shared__ float sW[80], sb[16], sg[16], sbt[16], sWl[512];
    int t = threadIdx.x;
    if (t < 80) sW[t] = ldf(W, t, isbf);
    if (t < 16){ sb[t]=ldf(bias,t,isbf); sg[t]=ldf(lng,t,isbf); sbt[t]=ldf(lnb,t,isbf); }
    sWl[t]     = ldf(Wl, t,     isbf);
    sWl[t+256] = ldf(Wl, t+256, isbf);
    __syncthreads();
    long i = blockIdx.x*256 + t;
    float f[5];
    #pragma unroll
    for (int k=0;k<5;k++) f[k] = ldf(x, i*5+k, isbf);
    float h[16];
    #pragma unroll
    for (int c=0;c<16;c++){
        float a = sb[c];
        #pragma unroll
        for (int k=0;k<5;k++) a += f[k]*sW[k*16+c];
        h[c]=a;
    }
    float mu=0.f;
    #pragma unroll
    for (int c=0;c<16;c++) mu += h[c];
    mu *= (1.f/16.f);
    float var=0.f;
    #pragma unroll
    for (int c=0;c<16;c++){ float d=h[c]-mu; var += d*d; }
    var *= (1.f/16.f);
    float inv = rsqrtf(var + 1e-5f);
    float v[16];
    #pragma unroll
    for (int c=0;c<16;c++){
        float y = sg[c]*(h[c]-mu)*inv + sbt[c];
        v[c] = (y>0.f) ? y : 0.01f*y;
    }
    float o[32];
    #pragma unroll
    for (int c=0;c<32;c++) o[c]=0.f;
    #pragma unroll
    for (int k=0;k<16;k++){
        float xv=v[k];
        #pragma unroll
        for (int c=0;c<32;c++) o[c] += xv*sWl[k*32+c];
    }
    #pragma unroll
    for (int c=0;c<32;c++) o[c] = fin(o[c]);
    uint4* op = (uint4*)(xl + i*16);
    #pragma unroll
    for (int q=0;q<4;q++)
        op[q] = make_uint4(pk2(o[q*8],o[q*8+1]), pk2(o[q*8+2],o[q*8+3]),
                           pk2(o[q*8+4],o[q*8+5]), pk2(o[q*8+6],o[q*8+7]));
}

// ---------------- phase 1: LDS-staged coarse bucket scatter ----------------
// packed edge: src (18 bits) | dloc=slot&511 (9 bits) << 18
__global__ __launch_bounds__(256) void bucket_scatter_kernel(
    const int* __restrict__ ei_dt, const int* __restrict__ mask_dt,
    const int* __restrict__ ei_tt,
    int* __restrict__ bktCur, unsigned* __restrict__ ebuf)
{
    __shared__ int shc[NBKT];
    __shared__ int sloff[NBKT];
    __shared__ int slcur[NBKT];
    __shared__ int spart[256];
    __shared__ unsigned stage[CH];   // 32 KB
    int t = threadIdx.x;
    long e0 = (long)blockIdx.x * CH;
    for (int b=t; b<NBKT; b+=256) shc[b]=0;
    __syncthreads();
    for (int i=t; i<CH; i+=256){
        long e = e0 + i;
        int slot, keep;
        if (e < EDT){ keep = mask_dt[e]; slot = ei_dt[EDT+e]; }
        else { long e2 = e-EDT; keep = 1; slot = NT + ei_tt[ETT+e2]; }
        if (keep) atomicAdd(&shc[slot>>9], 1);
    }
    __syncthreads();
    int b4 = t*4;
    int a0=shc[b4], a1=shc[b4+1], a2=shc[b4+2], a3=shc[b4+3];
    int lsum = a0+a1+a2+a3;
    spart[t] = lsum;
    __syncthreads();
    for (int off=1; off<256; off<<=1){
        int x = spart[t];
        int add = (t>=off) ? spart[t-off] : 0;
        __syncthreads();
        spart[t] = x + add;
        __syncthreads();
    }
    int run = spart[t] - lsum;
    int totKept = spart[255];
    sloff[b4]=run;   slcur[b4]=run;   run+=a0;
    sloff[b4+1]=run; slcur[b4+1]=run; run+=a1;
    sloff[b4+2]=run; slcur[b4+2]=run; run+=a2;
    sloff[b4+3]=run; slcur[b4+3]=run;
    if (a0>0) shc[b4]   = atomicAdd(&bktCur[b4],   a0);
    if (a1>0) shc[b4+1] = atomicAdd(&bktCur[b4+1], a1);
    if (a2>0) shc[b4+2] = atomicAdd(&bktCur[b4+2], a2);
    if (a3>0) shc[b4+3] = atomicAdd(&bktCur[b4+3], a3);
    __syncthreads();
    for (int i=t; i<CH; i+=256){
        long e = e0 + i;
        int slot, keep, s;
        if (e < EDT){ keep = mask_dt[e]; s = ei_dt[e]; slot = ei_dt[EDT+e]; }
        else { long e2 = e-EDT; keep = 1; s = ei_tt[e2]; slot = NT + ei_tt[ETT+e2]; }
        if (keep){
            int b = slot>>9;
            int pos = atomicAdd(&slcur[b], 1);
            stage[pos] = (unsigned)s | ((unsigned)(slot & 511) << 18);
        }
    }
    __syncthreads();
    for (int i=t; i<totKept; i+=256){
        int lo=0, hi=NBKT-1;
        while (lo<hi){ int mid=(lo+hi+1)>>1; if (sloff[mid]<=i) lo=mid; else hi=mid-1; }
        ebuf[shc[lo] + (i - sloff[lo])] = stage[i];
    }
}

// ---------------- phase 2: per-bucket LDS CSR + GAT aggregation ----------------
// R10 structure (1 dst/thread, 2 serial halves, register accumulation) with
// software-prefetched edge loop: load edge e+1's row while computing edge e.
// __launch_bounds__(256,2) pins VGPR cap at 256 so the prefetch regs cannot
// drop occupancy to 1 wave/SIMD.
__global__ __launch_bounds__(256, 2) void bucket_aggregate_kernel(
    const int* __restrict__ bktCur, const unsigned* __restrict__ ebuf,
    const float* __restrict__ xt,
    const unsigned* __restrict__ xl_dt, const unsigned* __restrict__ xl_tt,
    const void* __restrict__ dt_Wr, const void* __restrict__ tt_Wr,
    const void* __restrict__ dt_att, const void* __restrict__ tt_att,
    float* __restrict__ agg, const int* __restrict__ flag)
{
    __shared__ float sWr[512], satt[32];
    __shared__ int scnt[SPB], soff[SPB], scur[SPB], spart[256];
    __shared__ unsigned slist[BCAP];
    int t = threadIdx.x;
    int b = blockIdx.x;
    int which = (b >= NBKT/2);
    int isbf = *flag;
    const void* Wr  = which ? tt_Wr  : dt_Wr;
    const void* att = which ? tt_att : dt_att;
    sWr[t]     = ldf(Wr, t,     isbf);
    sWr[t+256] = ldf(Wr, t+256, isbf);
    if (t < 32) satt[t] = ldf(att, t, isbf);
    scnt[t] = 0; scnt[t+256] = 0;
    __syncthreads();
    int base = b*BCAP;
    int ecnt = bktCur[b] - base;
    if (ecnt > BCAP) ecnt = BCAP;
    if (ecnt < 0) ecnt = 0;
    for (int i=t; i<ecnt; i+=256)
        atomicAdd(&scnt[ebuf[base+i] >> 18], 1);
    __syncthreads();
    int c0 = scnt[2*t], c1 = scnt[2*t+1];
    int ls = c0 + c1;
    spart[t] = ls;
    __syncthreads();
    for (int off=1; off<256; off<<=1){
        int x = spart[t];
        int add = (t>=off) ? spart[t-off] : 0;
        __syncthreads();
        spart[t] = x + add;
        __syncthreads();
    }
    int run = spart[t] - ls;
    soff[2*t] = run; scur[2*t] = run;
    soff[2*t+1] = run + c0; scur[2*t+1] = run + c0;
    __syncthreads();
    for (int i=t; i<ecnt; i+=256){
        unsigned p = ebuf[base+i];
        int pos = atomicAdd(&scur[p >> 18], 1);
        slist[pos] = p & 0x3FFFFu;
    }
    __syncthreads();
    // aggregate: 2 dsts per thread (serial halves), prefetched edge loop
    const unsigned* xl = which ? xl_tt : xl_dt;
    for (int half=0; half<2; half++){
        int dloc = t + half*256;
        long slot = (long)b*SPB + dloc;
        long d = which ? slot - NT : slot;
        const float4* xp = (const float4*)(xt + d*16);
        float4 x0=xp[0], x1=xp[1], x2=xp[2], x3=xp[3];
        float xtv[16] = {x0.x,x0.y,x0.z,x0.w, x1.x,x1.y,x1.z,x1.w,
                         x2.x,x2.y,x2.z,x2.w, x3.x,x3.y,x3.z,x3.w};
        float xrv[32];
        #pragma unroll
        for (int c=0;c<32;c++) xrv[c]=0.f;
        #pragma unroll
        for (int k=0;k<16;k++){
            float xv=xtv[k];
            #pragma unroll
            for (int c=0;c<32;c++) xrv[c] += xv*sWr[k*32+c];
        }
        float acc[32];
        #pragma unroll
        for (int c=0;c<32;c++) acc[c]=0.f;
        float den0=0.f, den1=0.f;
        int e0 = soff[dloc], e1 = scur[dloc];
        uint4 u0, u1, u2, u3;
        if (e0 < e1){
            long s = slist[e0];
            const uint4* p = (const uint4*)(xl + s*16);
            u0 = p[0]; u1 = p[1]; u2 = p[2]; u3 = p[3];
        }
        for (int e=e0; e<e1; e++){
            uint4 n0, n1, n2, n3;
            if (e+1 < e1){
                long sn = slist[e+1];
                const uint4* np = (const uint4*)(xl + sn*16);
                n0 = np[0]; n1 = np[1]; n2 = np[2]; n3 = np[3];
            }
            float sc0 = score8(u0, xrv,    satt)    + score8(u1, xrv+8,  satt+8);
            float sc1 = score8(u2, xrv+16, satt+16) + score8(u3, xrv+24, satt+24);
            float a0 = expf(fminf(fin(sc0), 60.f));
            float a1 = expf(fminf(fin(sc1), 60.f));
            den0 += a0; den1 += a1;
            acc8(u0, a0, acc);    acc8(u1, a0, acc+8);
            acc8(u2, a1, acc+16); acc8(u3, a1, acc+24);
            u0 = n0; u1 = n1; u2 = n2; u3 = n3;
        }
        float id0 = 1.f/fmaxf(den0, 1e-16f);
        float id1 = 1.f/fmaxf(den1, 1e-16f);
        float4* op = (float4*)(agg + slot*16);
        #pragma unroll
        for (int q=0;q<4;q++){
            op[q] = make_float4(
                fin(0.5f*(acc[q*4  ]*id0 + acc[16+q*4  ]*id1)),
                fin(0.5f*(acc[q*4+1]*id0 + acc[16+q*4+1]*id1)),
                fin(0.5f*(acc[q*4+2]*id0 + acc[16+q*4+2]*id1)),
                fin(0.5f*(acc[q*4+3]*id0 + acc[16+q*4+3]*id1)));
        }
    }
}

__device__ __forceinline__ void ln_act16(const float* v, const float* g, const float* b, float* o){
    float mu=0.f;
    #pragma unroll
    for (int c=0;c<16;c++) mu += v[c];
    mu *= (1.f/16.f);
    float var=0.f;
    #pragma unroll
    for (int c=0;c<16;c++){ float d=v[c]-mu; var += d*d; }
    var *= (1.f/16.f);
    float inv = rsqrtf(var + 1e-5f);
    #pragma unroll
    for (int c=0;c<16;c++){
        float y = g[c]*(v[c]-mu)*inv + b[c];
        o[c] = (y>0.f) ? y : 0.01f*y;
    }
}

// ---------------- fuse + pooling (wave-shuffle reduction) ----------------
__global__ __launch_bounds__(256) void fuse_pool_kernel(
    const float* __restrict__ xt,
    const float* __restrict__ agg_dt, const float* __restrict__ agg_tt,
    const void* __restrict__ dt_res, const void* __restrict__ dt_bias,
    const void* __restrict__ tt_res, const void* __restrict__ tt_bias,
    const void* __restrict__ ln1g, const void* __restrict__ ln1b,
    const void* __restrict__ ln2g, const void* __restrict__ ln2b,
    const int* __restrict__ b_tasks, const int* __restrict__ ptrg,
    float* __restrict__ pool_sums, float* __restrict__ pool_cnt,
    void* __restrict__ out, const int* __restrict__ flag)
{
    int isbf = *flag;
    __shared__ float sdt[256], stt[256], sdb[16], stb[16], s1g[16], s1b[16], s2g[16], s2b[16];
    __shared__ float swave[4*48];
    __shared__ int sptr[16];
    __shared__ int s_nonuni;
    int t = threadIdx.x;
    sdt[t] = ldf(dt_res, t, isbf);
    stt[t] = ldf(tt_res, t, isbf);
    if (t < 16){
        sdb[t]=ldf(dt_bias,t,isbf); stb[t]=ldf(tt_bias,t,isbf);
        s1g[t]=ldf(ln1g,t,isbf); s1b[t]=ldf(ln1b,t,isbf);
        s2g[t]=ldf(ln2g,t,isbf); s2b[t]=ldf(ln2b,t,isbf);
        sptr[t]=ptrg[t];
    }
    if (t==0) s_nonuni = 0;
    __syncthreads();
    long i = blockIdx.x*256 + t;
    const float4* xp = (const float4*)(xt + i*16);
    float4 x0=xp[0], x1=xp[1], x2=xp[2], x3=xp[3];
    float vals[48];
    float* xv   = vals;
    float* tupd = vals+16;
    float* dupd = vals+32;
    xv[0]=x0.x; xv[1]=x0.y; xv[2]=x0.z; xv[3]=x0.w;
    xv[4]=x1.x; xv[5]=x1.y; xv[6]=x1.z; xv[7]=x1.w;
    xv[8]=x2.x; xv[9]=x2.y; xv[10]=x2.z; xv[11]=x2.w;
    xv[12]=x3.x; xv[13]=x3.y; xv[14]=x3.z; xv[15]=x3.w;
    {
        const float* ag = agg_dt + i*16;
        float v[16];
        #pragma unroll
        for (int c=0;c<16;c++){
            float r = sdb[c];
            #pragma unroll
            for (int k=0;k<16;k++) r += xv[k]*sdt[k*16+c];
            v[c] = fin(ag[c] + r);
        }
        ln_act16(v, s1g, s1b, dupd);
    }
    {
        const float* ag = agg_tt + i*16;
        float v[16];
        #pragma unroll
        for (int c=0;c<16;c++){
            float r = stb[c];
            #pragma unroll
            for (int k=0;k<16;k++) r += xv[k]*stt[k*16+c];
            v[c] = fin(ag[c] + r);
        }
        ln_act16(v, s2g, s2b, tupd);
    }
    #pragma unroll
    for (int j=0;j<48;j++) vals[j] = fin(vals[j]);
    #pragma unroll
    for (int g=0; g<16; g++){
        if (i == sptr[g]){
            for (int j=0;j<48;j++) stf(out, g*96+j, vals[j], isbf);
        }
    }
    int gi = b_tasks[i];
    int g0 = b_tasks[blockIdx.x*256];
    if (gi != g0) s_nonuni = 1;
    __syncthreads();
    if (s_nonuni){
        for (int j=0;j<48;j++) atomicAdd(&pool_sums[gi*48+j], vals[j]);
        atomicAdd(&pool_cnt[gi], 1.f);
    } else {
        int lane = t & 63, wid = t >> 6;
        #pragma unroll
        for (int j=0;j<48;j++){
            float v = vals[j];
            v += __shfl_down(v, 32);
            v += __shfl_down(v, 16);
            v += __shfl_down(v, 8);
            v += __shfl_down(v, 4);
            v += __shfl_down(v, 2);
            v += __shfl_down(v, 1);
            if (lane==0) swave[wid*48+j] = v;
        }
        __syncthreads();
        if (t < 48){
            float s = swave[t] + swave[48+t] + swave[96+t] + swave[144+t];
            atomicAdd(&pool_sums[g0*48+t], s);
        }
        if (t == 0) atomicAdd(&pool_cnt[g0], 256.f);
    }
}

__global__ void finish_kernel(const float* __restrict__ sums, const float* __restrict__ cnt,
                              void* __restrict__ out, const int* __restrict__ flag)
{
    int t = threadIdx.x;
    if (t >= 768) return;
    int g = t/48, c = t - g*48;
    stf(out, g*96+48+c, fin(sums[g*48+c]/fmaxf(cnt[g],1.f)), *flag);
}

extern "C" void kernel_launch(void* const* d_in, const int* in_sizes, int n_in,
                              void* d_out, int out_size, void* d_ws, size_t ws_size,
                              hipStream_t stream)
{
    const void* x_tasks  = d_in[0];
    const void* x_data   = d_in[1];
    const void* stem_t_W = d_in[2];
    const void* stem_t_b = d_in[3];
    const void* stem_d_W = d_in[4];
    const void* stem_d_b = d_in[5];
    const void* ln_t_g   = d_in[6];
    const void* ln_t_b   = d_in[7];
    const void* ln_d_g   = d_in[8];
    const void* ln_d_b   = d_in[9];
    const void* dt_Wl    = d_in[10];
    const void* dt_Wr    = d_in[11];
    const void* dt_att   = d_in[12];
    const void* dt_res   = d_in[13];
    const void* dt_bias  = d_in[14];
    const void* tt_Wl    = d_in[15];
    const void* tt_Wr    = d_in[16];
    const void* tt_att   = d_in[17];
    const void* tt_res   = d_in[18];
    const void* tt_bias  = d_in[19];
    const void* ln1_g    = d_in[20];
    const void* ln1_b    = d_in[21];
    const void* ln2_g    = d_in[22];
    const void* ln2_b    = d_in[23];
    const int*  ei_dt    = (const int*)d_in[24];
    const int*  mask_dt  = (const int*)d_in[25];
    const int*  ei_tt    = (const int*)d_in[26];
    const int*  b_tasks  = (const int*)d_in[27];
    const int*  ptrg     = (const int*)d_in[28];

    char* w = (char*)d_ws;
    const size_t MB = 1ull<<20;
    float*    xt        = (float*)(w);              // 16 MB  [NT,16] fp32
    unsigned* xl_dt     = (unsigned*)(w + 16*MB);   // 16 MB  [ND,16] bf16x2-packed
    unsigned* xl_tt     = (unsigned*)(w + 32*MB);   // 16 MB  [NT,16] bf16x2-packed
    float*    agg       = (float*)(w + 48*MB);      // 32 MB  [NSLOT,16] fp32
    unsigned* ebuf      = (unsigned*)(w + 80*MB);   // 12 MB (NBKT*BCAP) + slack
    int*      bktCur    = (int*)  (w + 93*MB);      // 4 KB
    float*    pool_sums = (float*)(w + 93*MB + 8192);
    float*    pool_cnt  = (float*)(w + 93*MB + 12288);
    int*      flag      = (int*)  (w + 93*MB + 16384);

    detect_kernel<<<1, 256, 0, stream>>>((const unsigned*)x_tasks, flag);
    init_cursors_kernel<<<(NBKT+255)/256, 256, 0, stream>>>(bktCur);
    hipMemsetAsync(w + 93*MB + 8192, 0, 8192, stream);

    // stems
    stem_task_kernel<<<NT/256, 256, 0, stream>>>(x_tasks, stem_t_W, stem_t_b, ln_t_g, ln_t_b,
                                                 tt_Wl, xt, xl_tt, flag);
    stem_data_transform_kernel<<<ND/256, 256, 0, stream>>>(x_data, stem_d_W, stem_d_b,
                                                           ln_d_g, ln_d_b, dt_Wl, xl_dt, flag);

    // phase 1: coarse bucket scatter (both graphs)
    bucket_scatter_kernel<<<NBLK1, 256, 0, stream>>>(ei_dt, mask_dt, ei_tt, bktCur, ebuf);

    // phase 2: per-bucket LDS CSR + aggregation (both graphs)
    bucket_aggregate_kernel<<<NBKT, 256, 0, stream>>>(bktCur, ebuf, xt, xl_dt, xl_tt,
        dt_Wr, tt_Wr, dt_att, tt_att, agg, flag);

    // fuse + pool + output
    fuse_pool_kernel<<<NT/256, 256, 0, stream>>>(xt, agg, agg + (long)NT*16,
        dt_res, dt_bias, tt_res, tt_bias, ln1_g, ln1_b, ln2_g, ln2_b,
        b_tasks, ptrg, pool_sums, pool_cnt, d_out, flag);
    finish_kernel<<<1, 768, 0, stream>>>(pool_sums, pool_cnt, d_out, flag);
}

// Round 13
// 438.727 us; speedup vs baseline: 1.8729x; 1.8729x over previous
//
#include <hip/hip_runtime.h>
#include <hip/hip_bf16.h>

typedef __hip_bfloat16 bf16;

#define NT 262144
#define ND 262144
#define EDT 2097152
#define ETT 1048576
#define NSLOT (2*NT)            // [0,NT)=d2t dst slots, [NT,2NT)=tt dst slots
#define NE_TOT (EDT+ETT)        // 3145728
#define NBKT 1024               // coarse buckets, bucket = slot>>9
#define SPB 512                 // slots per bucket
#define BCAP 3072               // per-bucket ebuf capacity (mean ~2048)
#define CH 8192                 // edges per phase-1 block (32KB stage, 45KB LDS -> 3 blocks/CU)
#define NBLK1 (NE_TOT/CH)       // 384

// ---- dual-dtype load/store: isbf==1 -> bf16, else fp32 ----
__device__ __forceinline__ float ldf(const void* p, long i, int isbf){
    if (isbf) return __bfloat162float(((const bf16*)p)[i]);
    return ((const float*)p)[i];
}
__device__ __forceinline__ void stf(void* p, int i, float v, int isbf){
    if (isbf) ((bf16*)p)[i] = __float2bfloat16(v);
    else      ((float*)p)[i] = v;
}
__device__ __forceinline__ float fin(float x){
    return (x==x && x>-3e38f && x<3e38f) ? x : 0.f;
}
// ---- bf16x2 pack/unpack ----
__device__ __forceinline__ unsigned pk2(float a, float b){
    bf16 ha = __float2bfloat16(a), hb = __float2bfloat16(b);
    unsigned short ua = *(unsigned short*)&ha, ub = *(unsigned short*)&hb;
    return ((unsigned)ub<<16) | (unsigned)ua;
}
__device__ __forceinline__ float ulo(unsigned u){ return __uint_as_float(u<<16); }
__device__ __forceinline__ float uhi(unsigned u){ return __uint_as_float(u & 0xffff0000u); }

// score contribution of 8 packed channels (leaky_relu(x+xr)·att)
__device__ __forceinline__ float score8(uint4 u, const float* xr, const float* at){
    float s=0.f, m;
    m = ulo(u.x)+xr[0]; m = m>0.f?m:0.2f*m; s += m*at[0];
    m = uhi(u.x)+xr[1]; m = m>0.f?m:0.2f*m; s += m*at[1];
    m = ulo(u.y)+xr[2]; m = m>0.f?m:0.2f*m; s += m*at[2];
    m = uhi(u.y)+xr[3]; m = m>0.f?m:0.2f*m; s += m*at[3];
    m = ulo(u.z)+xr[4]; m = m>0.f?m:0.2f*m; s += m*at[4];
    m = uhi(u.z)+xr[5]; m = m>0.f?m:0.2f*m; s += m*at[5];
    m = ulo(u.w)+xr[6]; m = m>0.f?m:0.2f*m; s += m*at[6];
    m = uhi(u.w)+xr[7]; m = m>0.f?m:0.2f*m; s += m*at[7];
    return s;
}
__device__ __forceinline__ void acc8(uint4 u, float a, float* acc){
    acc[0] += a*ulo(u.x); acc[1] += a*uhi(u.x);
    acc[2] += a*ulo(u.y); acc[3] += a*uhi(u.y);
    acc[4] += a*ulo(u.z); acc[5] += a*uhi(u.z);
    acc[6] += a*ulo(u.w); acc[7] += a*uhi(u.w);
}

// ---- input dtype detection: low-16-bit exponent census (see R2 notes) ----
__global__ void detect_kernel(const unsigned* __restrict__ raw, int* __restrict__ flag){
    __shared__ int cnt;
    if (threadIdx.x==0) cnt = 0;
    __syncthreads();
    int c = 0;
    for (int i = threadIdx.x; i < 2048; i += 256){
        unsigned w = raw[i];
        unsigned e = (w >> 7) & 0xFFu;
        if (e >= 116u && e <= 134u) c++;
    }
    atomicAdd(&cnt, c);
    __syncthreads();
    if (threadIdx.x==0) *flag = (cnt > 1024) ? 1 : 0;
}

__global__ void init_cursors_kernel(int* __restrict__ bktCur){
    int i = blockIdx.x*256 + threadIdx.x;
    if (i < NBKT) bktCur[i] = i*BCAP;
}

// ---------------- task stem: x_tasks -> xt[NT,16], fused @tt_Wl -> xl_tt (bf16-packed) ----------------
__global__ __launch_bounds__(256) void stem_task_kernel(
    const void* __restrict__ x, const void* __restrict__ W, const void* __restrict__ bias,
    const void* __restrict__ lng, const void* __restrict__ lnb,
    const void* __restrict__ Wl_tt, float* __restrict__ xt, unsigned* __restrict__ xl_tt,
    const int* __restrict__ flag)
{
    int isbf = *flag;
    __shared__ float sW[192], sb[16], sg[16], sbt[16], sWl[512];
    int t = threadIdx.x;
    if (t < 192) sW[t] = ldf(W, t, isbf);
    if (t < 16){ sb[t]=ldf(bias,t,isbf); sg[t]=ldf(lng,t,isbf); sbt[t]=ldf(lnb,t,isbf); }
    sWl[t]     = ldf(Wl_tt, t,     isbf);
    sWl[t+256] = ldf(Wl_tt, t+256, isbf);
    __syncthreads();
    long i = blockIdx.x*256 + t;
    float f[12];
    #pragma unroll
    for (int k=0;k<12;k++) f[k] = ldf(x, i*12+k, isbf);
    float h[16];
    #pragma unroll
    for (int c=0;c<16;c++){
        float a = sb[c];
        #pragma unroll
        for (int k=0;k<12;k++) a += f[k]*sW[k*16+c];
        h[c]=a;
    }
    float mu=0.f;
    #pragma unroll
    for (int c=0;c<16;c++) mu += h[c];
    mu *= (1.f/16.f);
    float var=0.f;
    #pragma unroll
    for (int c=0;c<16;c++){ float d=h[c]-mu; var += d*d; }
    var *= (1.f/16.f);
    float inv = rsqrtf(var + 1e-5f);
    float v[16];
    #pragma unroll
    for (int c=0;c<16;c++){
        float y = sg[c]*(h[c]-mu)*inv + sbt[c];
        v[c] = fin((y>0.f) ? y : 0.01f*y);
    }
    float4* xp = (float4*)(xt + i*16);
    #pragma unroll
    for (int q=0;q<4;q++) xp[q] = make_float4(v[q*4],v[q*4+1],v[q*4+2],v[q*4+3]);
    float o[32];
    #pragma unroll
    for (int c=0;c<32;c++) o[c]=0.f;
    #pragma unroll
    for (int k=0;k<16;k++){
        float xv=v[k];
        #pragma unroll
        for (int c=0;c<32;c++) o[c] += xv*sWl[k*32+c];
    }
    #pragma unroll
    for (int c=0;c<32;c++) o[c] = fin(o[c]);
    uint4* op = (uint4*)(xl_tt + i*16);
    #pragma unroll
    for (int q=0;q<4;q++)
        op[q] = make_uint4(pk2(o[q*8],o[q*8+1]), pk2(o[q*8+2],o[q*8+3]),
                           pk2(o[q*8+4],o[q*8+5]), pk2(o[q*8+6],o[q*8+7]));
}

// data stem fused with @dt_Wl -> xl_dt (bf16-packed)
__global__ __launch_bounds__(256) void stem_data_transform_kernel(
    const void* __restrict__ x, const void* __restrict__ W, const void* __restrict__ bias,
    const void* __restrict__ lng, const void* __restrict__ lnb,
    const void* __restrict__ Wl, unsigned* __restrict__ xl,
    const int* __restrict__ flag)
{
    int isbf = *flag;
    __shared__ float sW[80], sb[16], sg[16], sbt[16], sWl[512];
    int t = threadIdx.x;
    if (t < 80) sW[t] = ldf(W, t, isbf);
    if (t < 16){ sb[t]=ldf(bias,t,isbf); sg[t]=ldf(lng,t,isbf); sbt[t]=ldf(lnb,t,isbf); }
    sWl[t]     = ldf(Wl, t,     isbf);
    sWl[t+256] = ldf(Wl, t+256, isbf);
    __syncthreads();
    long i = blockIdx.x*256 + t;
    float f[5];
    #pragma unroll
    for (int k=0;k<5;k++) f[k] = ldf(x, i*5+k, isbf);
    float h[16];
    #pragma unroll
    for (int c=0;c<16;c++){
        float a = sb[c];
        #pragma unroll
        for (int k=0;k<5;k++) a += f[k]*sW[k*16+c];
        h[c]=a;
    }
    float mu=0.f;
    #pragma unroll
    for (int c=0;c<16;c++) mu += h[c];
    mu *= (1.f/16.f);
    float var=0.f;
    #pragma unroll
    for (int c=0;c<16;c++){ float d=h[c]-mu; var += d*d; }
    var *= (1.f/16.f);
    float inv = rsqrtf(var + 1e-5f);
    float v[16];
    #pragma unroll
    for (int c=0;c<16;c++){
        float y = sg[c]*(h[c]-mu)*inv + sbt[c];
        v[c] = (y>0.f) ? y : 0.01f*y;
    }
    float o[32];
    #pragma unroll
    for (int c=0;c<32;c++) o[c]=0.f;
    #pragma unroll
    for (int k=0;k<16;k++){
        float xv=v[k];
        #pragma unroll
        for (int c=0;c<32;c++) o[c] += xv*sWl[k*32+c];
    }
    #pragma unroll
    for (int c=0;c<32;c++) o[c] = fin(o[c]);
    uint4* op = (uint4*)(xl + i*16);
    #pragma unroll
    for (int q=0;q<4;q++)
        op[q] = make_uint4(pk2(o[q*8],o[q*8+1]), pk2(o[q*8+2],o[q*8+3]),
                           pk2(o[q*8+4],o[q*8+5]), pk2(o[q*8+6],o[q*8+7]));
}

// ---------------- phase 1: LDS-staged coarse bucket scatter ----------------
// packed edge: src (18 bits) | dloc=slot&511 (9 bits) << 18
__global__ __launch_bounds__(256) void bucket_scatter_kernel(
    const int* __restrict__ ei_dt, const int* __restrict__ mask_dt,
    const int* __restrict__ ei_tt,
    int* __restrict__ bktCur, unsigned* __restrict__ ebuf)
{
    __shared__ int shc[NBKT];
    __shared__ int sloff[NBKT];
    __shared__ int slcur[NBKT];
    __shared__ int spart[256];
    __shared__ unsigned stage[CH];   // 32 KB
    int t = threadIdx.x;
    long e0 = (long)blockIdx.x * CH;
    for (int b=t; b<NBKT; b+=256) shc[b]=0;
    __syncthreads();
    for (int i=t; i<CH; i+=256){
        long e = e0 + i;
        int slot, keep;
        if (e < EDT){ keep = mask_dt[e]; slot = ei_dt[EDT+e]; }
        else { long e2 = e-EDT; keep = 1; slot = NT + ei_tt[ETT+e2]; }
        if (keep) atomicAdd(&shc[slot>>9], 1);
    }
    __syncthreads();
    int b4 = t*4;
    int a0=shc[b4], a1=shc[b4+1], a2=shc[b4+2], a3=shc[b4+3];
    int lsum = a0+a1+a2+a3;
    spart[t] = lsum;
    __syncthreads();
    for (int off=1; off<256; off<<=1){
        int x = spart[t];
        int add = (t>=off) ? spart[t-off] : 0;
        __syncthreads();
        spart[t] = x + add;
        __syncthreads();
    }
    int run = spart[t] - lsum;
    int totKept = spart[255];
    sloff[b4]=run;   slcur[b4]=run;   run+=a0;
    sloff[b4+1]=run; slcur[b4+1]=run; run+=a1;
    sloff[b4+2]=run; slcur[b4+2]=run; run+=a2;
    sloff[b4+3]=run; slcur[b4+3]=run;
    if (a0>0) shc[b4]   = atomicAdd(&bktCur[b4],   a0);
    if (a1>0) shc[b4+1] = atomicAdd(&bktCur[b4+1], a1);
    if (a2>0) shc[b4+2] = atomicAdd(&bktCur[b4+2], a2);
    if (a3>0) shc[b4+3] = atomicAdd(&bktCur[b4+3], a3);
    __syncthreads();
    for (int i=t; i<CH; i+=256){
        long e = e0 + i;
        int slot, keep, s;
        if (e < EDT){ keep = mask_dt[e]; s = ei_dt[e]; slot = ei_dt[EDT+e]; }
        else { long e2 = e-EDT; keep = 1; s = ei_tt[e2]; slot = NT + ei_tt[ETT+e2]; }
        if (keep){
            int b = slot>>9;
            int pos = atomicAdd(&slcur[b], 1);
            stage[pos] = (unsigned)s | ((unsigned)(slot & 511) << 18);
        }
    }
    __syncthreads();
    for (int i=t; i<totKept; i+=256){
        int lo=0, hi=NBKT-1;
        while (lo<hi){ int mid=(lo+hi+1)>>1; if (sloff[mid]<=i) lo=mid; else hi=mid-1; }
        ebuf[shc[lo] + (i - sloff[lo])] = stage[i];
    }
}

// ---------------- phase 2: per-bucket LDS CSR + GAT aggregation ----------------
// R10 structure exactly: 1 dst/thread, 2 serial halves, register accumulation,
// packed bf16 row gathers (one 64B line per edge). Natural register allocation
// (240 VGPR, 2 waves/SIMD, zero spill) — measured optimum; do not force bounds
// or prefetch (R9/R11/R12 all regressed via spill or LDS-bank conflicts).
__global__ __launch_bounds__(256) void bucket_aggregate_kernel(
    const int* __restrict__ bktCur, const unsigned* __restrict__ ebuf,
    const float* __restrict__ xt,
    const unsigned* __restrict__ xl_dt, const unsigned* __restrict__ xl_tt,
    const void* __restrict__ dt_Wr, const void* __restrict__ tt_Wr,
    const void* __restrict__ dt_att, const void* __restrict__ tt_att,
    float* __restrict__ agg, const int* __restrict__ flag)
{
    __shared__ float sWr[512], satt[32];
    __shared__ int scnt[SPB], soff[SPB], scur[SPB], spart[256];
    __shared__ unsigned slist[BCAP];
    int t = threadIdx.x;
    int b = blockIdx.x;
    int which = (b >= NBKT/2);
    int isbf = *flag;
    const void* Wr  = which ? tt_Wr  : dt_Wr;
    const void* att = which ? tt_att : dt_att;
    sWr[t]     = ldf(Wr, t,     isbf);
    sWr[t+256] = ldf(Wr, t+256, isbf);
    if (t < 32) satt[t] = ldf(att, t, isbf);
    scnt[t] = 0; scnt[t+256] = 0;
    __syncthreads();
    int base = b*BCAP;
    int ecnt = bktCur[b] - base;
    if (ecnt > BCAP) ecnt = BCAP;
    if (ecnt < 0) ecnt = 0;
    for (int i=t; i<ecnt; i+=256)
        atomicAdd(&scnt[ebuf[base+i] >> 18], 1);
    __syncthreads();
    int c0 = scnt[2*t], c1 = scnt[2*t+1];
    int ls = c0 + c1;
    spart[t] = ls;
    __syncthreads();
    for (int off=1; off<256; off<<=1){
        int x = spart[t];
        int add = (t>=off) ? spart[t-off] : 0;
        __syncthreads();
        spart[t] = x + add;
        __syncthreads();
    }
    int run = spart[t] - ls;
    soff[2*t] = run; scur[2*t] = run;
    soff[2*t+1] = run + c0; scur[2*t+1] = run + c0;
    __syncthreads();
    for (int i=t; i<ecnt; i+=256){
        unsigned p = ebuf[base+i];
        int pos = atomicAdd(&scur[p >> 18], 1);
        slist[pos] = p & 0x3FFFFu;
    }
    __syncthreads();
    // aggregate: 2 dsts per thread (serial halves)
    const unsigned* xl = which ? xl_tt : xl_dt;
    for (int half=0; half<2; half++){
        int dloc = t + half*256;
        long slot = (long)b*SPB + dloc;
        long d = which ? slot - NT : slot;
        const float4* xp = (const float4*)(xt + d*16);
        float4 x0=xp[0], x1=xp[1], x2=xp[2], x3=xp[3];
        float xtv[16] = {x0.x,x0.y,x0.z,x0.w, x1.x,x1.y,x1.z,x1.w,
                         x2.x,x2.y,x2.z,x2.w, x3.x,x3.y,x3.z,x3.w};
        float xrv[32];
        #pragma unroll
        for (int c=0;c<32;c++) xrv[c]=0.f;
        #pragma unroll
        for (int k=0;k<16;k++){
            float xv=xtv[k];
            #pragma unroll
            for (int c=0;c<32;c++) xrv[c] += xv*sWr[k*32+c];
        }
        float acc[32];
        #pragma unroll
        for (int c=0;c<32;c++) acc[c]=0.f;
        float den0=0.f, den1=0.f;
        int e0 = soff[dloc], e1 = scur[dloc];
        for (int e=e0; e<e1; e++){
            long s = slist[e];
            const uint4* p = (const uint4*)(xl + s*16);
            uint4 u0 = p[0], u1 = p[1], u2 = p[2], u3 = p[3];
            float sc0 = score8(u0, xrv,    satt)    + score8(u1, xrv+8,  satt+8);
            float sc1 = score8(u2, xrv+16, satt+16) + score8(u3, xrv+24, satt+24);
            float a0 = expf(fminf(fin(sc0), 60.f));
            float a1 = expf(fminf(fin(sc1), 60.f));
            den0 += a0; den1 += a1;
            acc8(u0, a0, acc);    acc8(u1, a0, acc+8);
            acc8(u2, a1, acc+16); acc8(u3, a1, acc+24);
        }
        float id0 = 1.f/fmaxf(den0, 1e-16f);
        float id1 = 1.f/fmaxf(den1, 1e-16f);
        float4* op = (float4*)(agg + slot*16);
        #pragma unroll
        for (int q=0;q<4;q++){
            op[q] = make_float4(
                fin(0.5f*(acc[q*4  ]*id0 + acc[16+q*4  ]*id1)),
                fin(0.5f*(acc[q*4+1]*id0 + acc[16+q*4+1]*id1)),
                fin(0.5f*(acc[q*4+2]*id0 + acc[16+q*4+2]*id1)),
                fin(0.5f*(acc[q*4+3]*id0 + acc[16+q*4+3]*id1)));
        }
    }
}

__device__ __forceinline__ void ln_act16(const float* v, const float* g, const float* b, float* o){
    float mu=0.f;
    #pragma unroll
    for (int c=0;c<16;c++) mu += v[c];
    mu *= (1.f/16.f);
    float var=0.f;
    #pragma unroll
    for (int c=0;c<16;c++){ float d=v[c]-mu; var += d*d; }
    var *= (1.f/16.f);
    float inv = rsqrtf(var + 1e-5f);
    #pragma unroll
    for (int c=0;c<16;c++){
        float y = g[c]*(v[c]-mu)*inv + b[c];
        o[c] = (y>0.f) ? y : 0.01f*y;
    }
}

// ---------------- fuse + pooling (wave-shuffle reduction) ----------------
__global__ __launch_bounds__(256) void fuse_pool_kernel(
    const float* __restrict__ xt,
    const float* __restrict__ agg_dt, const float* __restrict__ agg_tt,
    const void* __restrict__ dt_res, const void* __restrict__ dt_bias,
    const void* __restrict__ tt_res, const void* __restrict__ tt_bias,
    const void* __restrict__ ln1g, const void* __restrict__ ln1b,
    const void* __restrict__ ln2g, const void* __restrict__ ln2b,
    const int* __restrict__ b_tasks, const int* __restrict__ ptrg,
    float* __restrict__ pool_sums, float* __restrict__ pool_cnt,
    void* __restrict__ out, const int* __restrict__ flag)
{
    int isbf = *flag;
    __shared__ float sdt[256], stt[256], sdb[16], stb[16], s1g[16], s1b[16], s2g[16], s2b[16];
    __shared__ float swave[4*48];
    __shared__ int sptr[16];
    __shared__ int s_nonuni;
    int t = threadIdx.x;
    sdt[t] = ldf(dt_res, t, isbf);
    stt[t] = ldf(tt_res, t, isbf);
    if (t < 16){
        sdb[t]=ldf(dt_bias,t,isbf); stb[t]=ldf(tt_bias,t,isbf);
        s1g[t]=ldf(ln1g,t,isbf); s1b[t]=ldf(ln1b,t,isbf);
        s2g[t]=ldf(ln2g,t,isbf); s2b[t]=ldf(ln2b,t,isbf);
        sptr[t]=ptrg[t];
    }
    if (t==0) s_nonuni = 0;
    __syncthreads();
    long i = blockIdx.x*256 + t;
    const float4* xp = (const float4*)(xt + i*16);
    float4 x0=xp[0], x1=xp[1], x2=xp[2], x3=xp[3];
    float vals[48];
    float* xv   = vals;
    float* tupd = vals+16;
    float* dupd = vals+32;
    xv[0]=x0.x; xv[1]=x0.y; xv[2]=x0.z; xv[3]=x0.w;
    xv[4]=x1.x; xv[5]=x1.y; xv[6]=x1.z; xv[7]=x1.w;
    xv[8]=x2.x; xv[9]=x2.y; xv[10]=x2.z; xv[11]=x2.w;
    xv[12]=x3.x; xv[13]=x3.y; xv[14]=x3.z; xv[15]=x3.w;
    {
        const float* ag = agg_dt + i*16;
        float v[16];
        #pragma unroll
        for (int c=0;c<16;c++){
            float r = sdb[c];
            #pragma unroll
            for (int k=0;k<16;k++) r += xv[k]*sdt[k*16+c];
            v[c] = fin(ag[c] + r);
        }
        ln_act16(v, s1g, s1b, dupd);
    }
    {
        const float* ag = agg_tt + i*16;
        float v[16];
        #pragma unroll
        for (int c=0;c<16;c++){
            float r = stb[c];
            #pragma unroll
            for (int k=0;k<16;k++) r += xv[k]*stt[k*16+c];
            v[c] = fin(ag[c] + r);
        }
        ln_act16(v, s2g, s2b, tupd);
    }
    #pragma unroll
    for (int j=0;j<48;j++) vals[j] = fin(vals[j]);
    #pragma unroll
    for (int g=0; g<16; g++){
        if (i == sptr[g]){
            for (int j=0;j<48;j++) stf(out, g*96+j, vals[j], isbf);
        }
    }
    int gi = b_tasks[i];
    int g0 = b_tasks[blockIdx.x*256];
    if (gi != g0) s_nonuni = 1;
    __syncthreads();
    if (s_nonuni){
        for (int j=0;j<48;j++) atomicAdd(&pool_sums[gi*48+j], vals[j]);
        atomicAdd(&pool_cnt[gi], 1.f);
    } else {
        int lane = t & 63, wid = t >> 6;
        #pragma unroll
        for (int j=0;j<48;j++){
            float v = vals[j];
            v += __shfl_down(v, 32);
            v += __shfl_down(v, 16);
            v += __shfl_down(v, 8);
            v += __shfl_down(v, 4);
            v += __shfl_down(v, 2);
            v += __shfl_down(v, 1);
            if (lane==0) swave[wid*48+j] = v;
        }
        __syncthreads();
        if (t < 48){
            float s = swave[t] + swave[48+t] + swave[96+t] + swave[144+t];
            atomicAdd(&pool_sums[g0*48+t], s);
        }
        if (t == 0) atomicAdd(&pool_cnt[g0], 256.f);
    }
}

__global__ void finish_kernel(const float* __restrict__ sums, const float* __restrict__ cnt,
                              void* __restrict__ out, const int* __restrict__ flag)
{
    int t = threadIdx.x;
    if (t >= 768) return;
    int g = t/48, c = t - g*48;
    stf(out, g*96+48+c, fin(sums[g*48+c]/fmaxf(cnt[g],1.f)), *flag);
}

extern "C" void kernel_launch(void* const* d_in, const int* in_sizes, int n_in,
                              void* d_out, int out_size, void* d_ws, size_t ws_size,
                              hipStream_t stream)
{
    const void* x_tasks  = d_in[0];
    const void* x_data   = d_in[1];
    const void* stem_t_W = d_in[2];
    const void* stem_t_b = d_in[3];
    const void* stem_d_W = d_in[4];
    const void* stem_d_b = d_in[5];
    const void* ln_t_g   = d_in[6];
    const void* ln_t_b   = d_in[7];
    const void* ln_d_g   = d_in[8];
    const void* ln_d_b   = d_in[9];
    const void* dt_Wl    = d_in[10];
    const void* dt_Wr    = d_in[11];
    const void* dt_att   = d_in[12];
    const void* dt_res   = d_in[13];
    const void* dt_bias  = d_in[14];
    const void* tt_Wl    = d_in[15];
    const void* tt_Wr    = d_in[16];
    const void* tt_att   = d_in[17];
    const void* tt_res   = d_in[18];
    const void* tt_bias  = d_in[19];
    const void* ln1_g    = d_in[20];
    const void* ln1_b    = d_in[21];
    const void* ln2_g    = d_in[22];
    const void* ln2_b    = d_in[23];
    const int*  ei_dt    = (const int*)d_in[24];
    const int*  mask_dt  = (const int*)d_in[25];
    const int*  ei_tt    = (const int*)d_in[26];
    const int*  b_tasks  = (const int*)d_in[27];
    const int*  ptrg     = (const int*)d_in[28];

    char* w = (char*)d_ws;
    const size_t MB = 1ull<<20;
    float*    xt        = (float*)(w);              // 16 MB  [NT,16] fp32
    unsigned* xl_dt     = (unsigned*)(w + 16*MB);   // 16 MB  [ND,16] bf16x2-packed
    unsigned* xl_tt     = (unsigned*)(w + 32*MB);   // 16 MB  [NT,16] bf16x2-packed
    float*    agg       = (float*)(w + 48*MB);      // 32 MB  [NSLOT,16] fp32
    unsigned* ebuf      = (unsigned*)(w + 80*MB);   // 12 MB (NBKT*BCAP) + slack
    int*      bktCur    = (int*)  (w + 93*MB);      // 4 KB
    float*    pool_sums = (float*)(w + 93*MB + 8192);
    float*    pool_cnt  = (float*)(w + 93*MB + 12288);
    int*      flag      = (int*)  (w + 93*MB + 16384);

    detect_kernel<<<1, 256, 0, stream>>>((const unsigned*)x_tasks, flag);
    init_cursors_kernel<<<(NBKT+255)/256, 256, 0, stream>>>(bktCur);
    hipMemsetAsync(w + 93*MB + 8192, 0, 8192, stream);

    // stems
    stem_task_kernel<<<NT/256, 256, 0, stream>>>(x_tasks, stem_t_W, stem_t_b, ln_t_g, ln_t_b,
                                                 tt_Wl, xt, xl_tt, flag);
    stem_data_transform_kernel<<<ND/256, 256, 0, stream>>>(x_data, stem_d_W, stem_d_b,
                                                           ln_d_g, ln_d_b, dt_Wl, xl_dt, flag);

    // phase 1: coarse bucket scatter (both graphs)
    bucket_scatter_kernel<<<NBLK1, 256, 0, stream>>>(ei_dt, mask_dt, ei_tt, bktCur, ebuf);

    // phase 2: per-bucket LDS CSR + aggregation (both graphs)
    bucket_aggregate_kernel<<<NBKT, 256, 0, stream>>>(bktCur, ebuf, xt, xl_dt, xl_tt,
        dt_Wr, tt_Wr, dt_att, tt_att, agg, flag);

    // fuse + pool + output
    fuse_pool_kernel<<<NT/256, 256, 0, stream>>>(xt, agg, agg + (long)NT*16,
        dt_res, dt_bias, tt_res, tt_bias, ln1_g, ln1_b, ln2_g, ln2_b,
        b_tasks, ptrg, pool_sums, pool_cnt, d_out, flag);
    finish_kernel<<<1, 768, 0, stream>>>(pool_sums, pool_cnt, d_out, flag);
}

// Round 14
// 406.447 us; speedup vs baseline: 2.0216x; 1.0794x over previous
//
#include <hip/hip_runtime.h>
#include <hip/hip_bf16.h>

typedef __hip_bfloat16 bf16;

#define NT 262144
#define ND 262144
#define EDT 2097152
#define ETT 1048576
#define NSLOT (2*NT)            // [0,NT)=d2t dst slots, [NT,2NT)=tt dst slots
#define NE_TOT (EDT+ETT)        // 3145728
#define NBKT 1024               // coarse buckets, bucket = slot>>9
#define SPB 512                 // slots per bucket
#define BCAP 3072               // per-bucket ebuf capacity (mean ~2048)
#define CH 8192                 // edges per phase-1 block (32KB stage, 45KB LDS -> 3 blocks/CU)
#define NBLK1 (NE_TOT/CH)       // 384

// ---- dual-dtype load/store: isbf==1 -> bf16, else fp32 ----
__device__ __forceinline__ float ldf(const void* p, long i, int isbf){
    if (isbf) return __bfloat162float(((const bf16*)p)[i]);
    return ((const float*)p)[i];
}
__device__ __forceinline__ void stf(void* p, int i, float v, int isbf){
    if (isbf) ((bf16*)p)[i] = __float2bfloat16(v);
    else      ((float*)p)[i] = v;
}
__device__ __forceinline__ float fin(float x){
    return (x==x && x>-3e38f && x<3e38f) ? x : 0.f;
}
// ---- bf16x2 pack/unpack ----
__device__ __forceinline__ unsigned pk2(float a, float b){
    bf16 ha = __float2bfloat16(a), hb = __float2bfloat16(b);
    unsigned short ua = *(unsigned short*)&ha, ub = *(unsigned short*)&hb;
    return ((unsigned)ub<<16) | (unsigned)ua;
}
__device__ __forceinline__ float ulo(unsigned u){ return __uint_as_float(u<<16); }
__device__ __forceinline__ float uhi(unsigned u){ return __uint_as_float(u & 0xffff0000u); }

// score contribution of 8 packed channels (leaky_relu(x+xr)·att)
__device__ __forceinline__ float score8(uint4 u, const float* xr, const float* at){
    float s=0.f, m;
    m = ulo(u.x)+xr[0]; m = m>0.f?m:0.2f*m; s += m*at[0];
    m = uhi(u.x)+xr[1]; m = m>0.f?m:0.2f*m; s += m*at[1];
    m = ulo(u.y)+xr[2]; m = m>0.f?m:0.2f*m; s += m*at[2];
    m = uhi(u.y)+xr[3]; m = m>0.f?m:0.2f*m; s += m*at[3];
    m = ulo(u.z)+xr[4]; m = m>0.f?m:0.2f*m; s += m*at[4];
    m = uhi(u.z)+xr[5]; m = m>0.f?m:0.2f*m; s += m*at[5];
    m = ulo(u.w)+xr[6]; m = m>0.f?m:0.2f*m; s += m*at[6];
    m = uhi(u.w)+xr[7]; m = m>0.f?m:0.2f*m; s += m*at[7];
    return s;
}
__device__ __forceinline__ void acc8(uint4 u, float a, float* acc){
    acc[0] += a*ulo(u.x); acc[1] += a*uhi(u.x);
    acc[2] += a*ulo(u.y); acc[3] += a*uhi(u.y);
    acc[4] += a*ulo(u.z); acc[5] += a*uhi(u.z);
    acc[6] += a*ulo(u.w); acc[7] += a*uhi(u.w);
}

// ---- input dtype detection: low-16-bit exponent census (see R2 notes) ----
__global__ void detect_kernel(const unsigned* __restrict__ raw, int* __restrict__ flag){
    __shared__ int cnt;
    if (threadIdx.x==0) cnt = 0;
    __syncthreads();
    int c = 0;
    for (int i = threadIdx.x; i < 2048; i += 256){
        unsigned w = raw[i];
        unsigned e = (w >> 7) & 0xFFu;
        if (e >= 116u && e <= 134u) c++;
    }
    atomicAdd(&cnt, c);
    __syncthreads();
    if (threadIdx.x==0) *flag = (cnt > 1024) ? 1 : 0;
}

__global__ void init_cursors_kernel(int* __restrict__ bktCur){
    int i = blockIdx.x*256 + threadIdx.x;
    if (i < NBKT) bktCur[i] = i*BCAP;
}

// ---------------- task stem: x_tasks -> xt[NT,16], fused @tt_Wl -> xl_tt (bf16-packed) ----------------
__global__ __launch_bounds__(256) void stem_task_kernel(
    const void* __restrict__ x, const void* __restrict__ W, const void* __restrict__ bias,
    const void* __restrict__ lng, const void* __restrict__ lnb,
    const void* __restrict__ Wl_tt, float* __restrict__ xt, unsigned* __restrict__ xl_tt,
    const int* __restrict__ flag)
{
    int isbf = *flag;
    __shared__ float sW[192], sb[16], sg[16], sbt[16], sWl[512];
    int t = threadIdx.x;
    if (t < 192) sW[t] = ldf(W, t, isbf);
    if (t < 16){ sb[t]=ldf(bias,t,isbf); sg[t]=ldf(lng,t,isbf); sbt[t]=ldf(lnb,t,isbf); }
    sWl[t]     = ldf(Wl_tt, t,     isbf);
    sWl[t+256] = ldf(Wl_tt, t+256, isbf);
    __syncthreads();
    long i = blockIdx.x*256 + t;
    float f[12];
    #pragma unroll
    for (int k=0;k<12;k++) f[k] = ldf(x, i*12+k, isbf);
    float h[16];
    #pragma unroll
    for (int c=0;c<16;c++){
        float a = sb[c];
        #pragma unroll
        for (int k=0;k<12;k++) a += f[k]*sW[k*16+c];
        h[c]=a;
    }
    float mu=0.f;
    #pragma unroll
    for (int c=0;c<16;c++) mu += h[c];
    mu *= (1.f/16.f);
    float var=0.f;
    #pragma unroll
    for (int c=0;c<16;c++){ float d=h[c]-mu; var += d*d; }
    var *= (1.f/16.f);
    float inv = rsqrtf(var + 1e-5f);
    float v[16];
    #pragma unroll
    for (int c=0;c<16;c++){
        float y = sg[c]*(h[c]-mu)*inv + sbt[c];
        v[c] = fin((y>0.f) ? y : 0.01f*y);
    }
    float4* xp = (float4*)(xt + i*16);
    #pragma unroll
    for (int q=0;q<4;q++) xp[q] = make_float4(v[q*4],v[q*4+1],v[q*4+2],v[q*4+3]);
    float o[32];
    #pragma unroll
    for (int c=0;c<32;c++) o[c]=0.f;
    #pragma unroll
    for (int k=0;k<16;k++){
        float xv=v[k];
        #pragma unroll
        for (int c=0;c<32;c++) o[c] += xv*sWl[k*32+c];
    }
    #pragma unroll
    for (int c=0;c<32;c++) o[c] = fin(o[c]);
    uint4* op = (uint4*)(xl_tt + i*16);
    #pragma unroll
    for (int q=0;q<4;q++)
        op[q] = make_uint4(pk2(o[q*8],o[q*8+1]), pk2(o[q*8+2],o[q*8+3]),
                           pk2(o[q*8+4],o[q*8+5]), pk2(o[q*8+6],o[q*8+7]));
}

// data stem fused with @dt_Wl -> xl_dt (bf16-packed)
__global__ __launch_bounds__(256) void stem_data_transform_kernel(
    const void* __restrict__ x, const void* __restrict__ W, const void* __restrict__ bias,
    const void* __restrict__ lng, const void* __restrict__ lnb,
    const void* __restrict__ Wl, unsigned* __restrict__ xl,
    const int* __restrict__ flag)
{
    int isbf = *flag;
    __shared__ float sW[80], sb[16], sg[16], sbt[16], sWl[512];
    int t = threadIdx.x;
    if (t < 80) sW[t] = ldf(W, t, isbf);
    if (t < 16){ sb[t]=ldf(bias,t,isbf); sg[t]=ldf(lng,t,isbf); sbt[t]=ldf(lnb,t,isbf); }
    sWl[t]     = ldf(Wl, t,     isbf);
    sWl[t+256] = ldf(Wl, t+256, isbf);
    __syncthreads();
    long i = blockIdx.x*256 + t;
    float f[5];
    #pragma unroll
    for (int k=0;k<5;k++) f[k] = ldf(x, i*5+k, isbf);
    float h[16];
    #pragma unroll
    for (int c=0;c<16;c++){
        float a = sb[c];
        #pragma unroll
        for (int k=0;k<5;k++) a += f[k]*sW[k*16+c];
        h[c]=a;
    }
    float mu=0.f;
    #pragma unroll
    for (int c=0;c<16;c++) mu += h[c];
    mu *= (1.f/16.f);
    float var=0.f;
    #pragma unroll
    for (int c=0;c<16;c++){ float d=h[c]-mu; var += d*d; }
    var *= (1.f/16.f);
    float inv = rsqrtf(var + 1e-5f);
    float v[16];
    #pragma unroll
    for (int c=0;c<16;c++){
        float y = sg[c]*(h[c]-mu)*inv + sbt[c];
        v[c] = (y>0.f) ? y : 0.01f*y;
    }
    float o[32];
    #pragma unroll
    for (int c=0;c<32;c++) o[c]=0.f;
    #pragma unroll
    for (int k=0;k<16;k++){
        float xv=v[k];
        #pragma unroll
        for (int c=0;c<32;c++) o[c] += xv*sWl[k*32+c];
    }
    #pragma unroll
    for (int c=0;c<32;c++) o[c] = fin(o[c]);
    uint4* op = (uint4*)(xl + i*16);
    #pragma unroll
    for (int q=0;q<4;q++)
        op[q] = make_uint4(pk2(o[q*8],o[q*8+1]), pk2(o[q*8+2],o[q*8+3]),
                           pk2(o[q*8+4],o[q*8+5]), pk2(o[q*8+6],o[q*8+7]));
}

// ---------------- phase 1: LDS-staged coarse bucket scatter ----------------
// packed edge: src (18 bits) | dloc=slot&511 (9 bits) << 18
__global__ __launch_bounds__(256) void bucket_scatter_kernel(
    const int* __restrict__ ei_dt, const int* __restrict__ mask_dt,
    const int* __restrict__ ei_tt,
    int* __restrict__ bktCur, unsigned* __restrict__ ebuf)
{
    __shared__ int shc[NBKT];
    __shared__ int sloff[NBKT];
    __shared__ int slcur[NBKT];
    __shared__ int spart[256];
    __shared__ unsigned stage[CH];   // 32 KB
    int t = threadIdx.x;
    long e0 = (long)blockIdx.x * CH;
    for (int b=t; b<NBKT; b+=256) shc[b]=0;
    __syncthreads();
    for (int i=t; i<CH; i+=256){
        long e = e0 + i;
        int slot, keep;
        if (e < EDT){ keep = mask_dt[e]; slot = ei_dt[EDT+e]; }
        else { long e2 = e-EDT; keep = 1; slot = NT + ei_tt[ETT+e2]; }
        if (keep) atomicAdd(&shc[slot>>9], 1);
    }
    __syncthreads();
    int b4 = t*4;
    int a0=shc[b4], a1=shc[b4+1], a2=shc[b4+2], a3=shc[b4+3];
    int lsum = a0+a1+a2+a3;
    spart[t] = lsum;
    __syncthreads();
    for (int off=1; off<256; off<<=1){
        int x = spart[t];
        int add = (t>=off) ? spart[t-off] : 0;
        __syncthreads();
        spart[t] = x + add;
        __syncthreads();
    }
    int run = spart[t] - lsum;
    int totKept = spart[255];
    sloff[b4]=run;   slcur[b4]=run;   run+=a0;
    sloff[b4+1]=run; slcur[b4+1]=run; run+=a1;
    sloff[b4+2]=run; slcur[b4+2]=run; run+=a2;
    sloff[b4+3]=run; slcur[b4+3]=run;
    if (a0>0) shc[b4]   = atomicAdd(&bktCur[b4],   a0);
    if (a1>0) shc[b4+1] = atomicAdd(&bktCur[b4+1], a1);
    if (a2>0) shc[b4+2] = atomicAdd(&bktCur[b4+2], a2);
    if (a3>0) shc[b4+3] = atomicAdd(&bktCur[b4+3], a3);
    __syncthreads();
    for (int i=t; i<CH; i+=256){
        long e = e0 + i;
        int slot, keep, s;
        if (e < EDT){ keep = mask_dt[e]; s = ei_dt[e]; slot = ei_dt[EDT+e]; }
        else { long e2 = e-EDT; keep = 1; s = ei_tt[e2]; slot = NT + ei_tt[ETT+e2]; }
        if (keep){
            int b = slot>>9;
            int pos = atomicAdd(&slcur[b], 1);
            stage[pos] = (unsigned)s | ((unsigned)(slot & 511) << 18);
        }
    }
    __syncthreads();
    for (int i=t; i<totKept; i+=256){
        int lo=0, hi=NBKT-1;
        while (lo<hi){ int mid=(lo+hi+1)>>1; if (sloff[mid]<=i) lo=mid; else hi=mid-1; }
        ebuf[shc[lo] + (i - sloff[lo])] = stage[i];
    }
}

// ---------------- phase 2: per-bucket LDS CSR + head-serial GAT aggregation ----------------
// Each dst's edge list is scanned twice, once per head (#pragma unroll 1 keeps
// passes serial). Per-pass live state ~ xr[16]+acc[16]+2xuint4 -> low VGPR ->
// more waves/SIMD for gather-latency hiding. Head-0 partial parked in LDS
// (stride-17, conflict-free; same-thread readback, no sync). No forced
// launch_bounds (R9/R12 lesson: forcing bounds => scratch spill).
__global__ __launch_bounds__(256) void bucket_aggregate_kernel(
    const int* __restrict__ bktCur, const unsigned* __restrict__ ebuf,
    const float* __restrict__ xt,
    const unsigned* __restrict__ xl_dt, const unsigned* __restrict__ xl_tt,
    const void* __restrict__ dt_Wr, const void* __restrict__ tt_Wr,
    const void* __restrict__ dt_att, const void* __restrict__ tt_att,
    float* __restrict__ agg, const int* __restrict__ flag)
{
    __shared__ float sWr[512], satt[32];
    __shared__ int scnt[SPB], soff[SPB], scur[SPB], spart[256];
    __shared__ unsigned slist[BCAP];
    __shared__ float sspill[256*17];   // head-0 normalized partials, stride 17
    int t = threadIdx.x;
    int b = blockIdx.x;
    int which = (b >= NBKT/2);
    int isbf = *flag;
    const void* Wr  = which ? tt_Wr  : dt_Wr;
    const void* att = which ? tt_att : dt_att;
    sWr[t]     = ldf(Wr, t,     isbf);
    sWr[t+256] = ldf(Wr, t+256, isbf);
    if (t < 32) satt[t] = ldf(att, t, isbf);
    scnt[t] = 0; scnt[t+256] = 0;
    __syncthreads();
    int base = b*BCAP;
    int ecnt = bktCur[b] - base;
    if (ecnt > BCAP) ecnt = BCAP;
    if (ecnt < 0) ecnt = 0;
    for (int i=t; i<ecnt; i+=256)
        atomicAdd(&scnt[ebuf[base+i] >> 18], 1);
    __syncthreads();
    int c0 = scnt[2*t], c1 = scnt[2*t+1];
    int ls = c0 + c1;
    spart[t] = ls;
    __syncthreads();
    for (int off=1; off<256; off<<=1){
        int x = spart[t];
        int add = (t>=off) ? spart[t-off] : 0;
        __syncthreads();
        spart[t] = x + add;
        __syncthreads();
    }
    int run = spart[t] - ls;
    soff[2*t] = run; scur[2*t] = run;
    soff[2*t+1] = run + c0; scur[2*t+1] = run + c0;
    __syncthreads();
    for (int i=t; i<ecnt; i+=256){
        unsigned p = ebuf[base+i];
        int pos = atomicAdd(&scur[p >> 18], 1);
        slist[pos] = p & 0x3FFFFu;
    }
    __syncthreads();
    // aggregate: 2 dsts per thread (serial halves) x 2 serial head passes
    const unsigned* xl = which ? xl_tt : xl_dt;
    #pragma unroll 1
    for (int half=0; half<2; half++){
        int dloc = t + half*256;
        long slot = (long)b*SPB + dloc;
        long d = which ? slot - NT : slot;
        int e0 = soff[dloc], e1 = scur[dloc];
        #pragma unroll 1
        for (int head=0; head<2; head++){
            // xr for this head only (xtv is dead after this block)
            const float4* xp = (const float4*)(xt + d*16);
            float4 x0=xp[0], x1=xp[1], x2=xp[2], x3=xp[3];
            float xtv[16] = {x0.x,x0.y,x0.z,x0.w, x1.x,x1.y,x1.z,x1.w,
                             x2.x,x2.y,x2.z,x2.w, x3.x,x3.y,x3.z,x3.w};
            float xr[16];
            #pragma unroll
            for (int c=0;c<16;c++) xr[c]=0.f;
            #pragma unroll
            for (int k=0;k<16;k++){
                float xv=xtv[k];
                #pragma unroll
                for (int c=0;c<16;c++) xr[c] += xv*sWr[k*32 + head*16 + c];
            }
            const float* at = satt + head*16;
            float acc[16];
            #pragma unroll
            for (int c=0;c<16;c++) acc[c]=0.f;
            float den=0.f;
            for (int e=e0; e<e1; e++){
                long s = slist[e];
                const uint4* p = (const uint4*)(xl + s*16 + head*8);
                uint4 u0 = p[0], u1 = p[1];
                float sc = score8(u0, xr, at) + score8(u1, xr+8, at+8);
                float a = expf(fminf(fin(sc), 60.f));
                den += a;
                acc8(u0, a, acc); acc8(u1, a, acc+8);
            }
            float id = 1.f/fmaxf(den, 1e-16f);
            if (head==0){
                #pragma unroll
                for (int c=0;c<16;c++) sspill[t*17+c] = acc[c]*id;
            } else {
                float4* op = (float4*)(agg + slot*16);
                #pragma unroll
                for (int q=0;q<4;q++){
                    float v[4];
                    #pragma unroll
                    for (int j=0;j<4;j++)
                        v[j] = fin(0.5f*(sspill[t*17+q*4+j] + acc[q*4+j]*id));
                    op[q] = make_float4(v[0],v[1],v[2],v[3]);
                }
            }
        }
    }
}

__device__ __forceinline__ void ln_act16(const float* v, const float* g, const float* b, float* o){
    float mu=0.f;
    #pragma unroll
    for (int c=0;c<16;c++) mu += v[c];
    mu *= (1.f/16.f);
    float var=0.f;
    #pragma unroll
    for (int c=0;c<16;c++){ float d=v[c]-mu; var += d*d; }
    var *= (1.f/16.f);
    float inv = rsqrtf(var + 1e-5f);
    #pragma unroll
    for (int c=0;c<16;c++){
        float y = g[c]*(v[c]-mu)*inv + b[c];
        o[c] = (y>0.f) ? y : 0.01f*y;
    }
}

// ---------------- fuse + pooling (wave-shuffle reduction) ----------------
__global__ __launch_bounds__(256) void fuse_pool_kernel(
    const float* __restrict__ xt,
    const float* __restrict__ agg_dt, const float* __restrict__ agg_tt,
    const void* __restrict__ dt_res, const void* __restrict__ dt_bias,
    const void* __restrict__ tt_res, const void* __restrict__ tt_bias,
    const void* __restrict__ ln1g, const void* __restrict__ ln1b,
    const void* __restrict__ ln2g, const void* __restrict__ ln2b,
    const int* __restrict__ b_tasks, const int* __restrict__ ptrg,
    float* __restrict__ pool_sums, float* __restrict__ pool_cnt,
    void* __restrict__ out, const int* __restrict__ flag)
{
    int isbf = *flag;
    __shared__ float sdt[256], stt[256], sdb[16], stb[16], s1g[16], s1b[16], s2g[16], s2b[16];
    __shared__ float swave[4*48];
    __shared__ int sptr[16];
    __shared__ int s_nonuni;
    int t = threadIdx.x;
    sdt[t] = ldf(dt_res, t, isbf);
    stt[t] = ldf(tt_res, t, isbf);
    if (t < 16){
        sdb[t]=ldf(dt_bias,t,isbf); stb[t]=ldf(tt_bias,t,isbf);
        s1g[t]=ldf(ln1g,t,isbf); s1b[t]=ldf(ln1b,t,isbf);
        s2g[t]=ldf(ln2g,t,isbf); s2b[t]=ldf(ln2b,t,isbf);
        sptr[t]=ptrg[t];
    }
    if (t==0) s_nonuni = 0;
    __syncthreads();
    long i = blockIdx.x*256 + t;
    const float4* xp = (const float4*)(xt + i*16);
    float4 x0=xp[0], x1=xp[1], x2=xp[2], x3=xp[3];
    float vals[48];
    float* xv   = vals;
    float* tupd = vals+16;
    float* dupd = vals+32;
    xv[0]=x0.x; xv[1]=x0.y; xv[2]=x0.z; xv[3]=x0.w;
    xv[4]=x1.x; xv[5]=x1.y; xv[6]=x1.z; xv[7]=x1.w;
    xv[8]=x2.x; xv[9]=x2.y; xv[10]=x2.z; xv[11]=x2.w;
    xv[12]=x3.x; xv[13]=x3.y; xv[14]=x3.z; xv[15]=x3.w;
    {
        const float* ag = agg_dt + i*16;
        float v[16];
        #pragma unroll
        for (int c=0;c<16;c++){
            float r = sdb[c];
            #pragma unroll
            for (int k=0;k<16;k++) r += xv[k]*sdt[k*16+c];
            v[c] = fin(ag[c] + r);
        }
        ln_act16(v, s1g, s1b, dupd);
    }
    {
        const float* ag = agg_tt + i*16;
        float v[16];
        #pragma unroll
        for (int c=0;c<16;c++){
            float r = stb[c];
            #pragma unroll
            for (int k=0;k<16;k++) r += xv[k]*stt[k*16+c];
            v[c] = fin(ag[c] + r);
        }
        ln_act16(v, s2g, s2b, tupd);
    }
    #pragma unroll
    for (int j=0;j<48;j++) vals[j] = fin(vals[j]);
    #pragma unroll
    for (int g=0; g<16; g++){
        if (i == sptr[g]){
            for (int j=0;j<48;j++) stf(out, g*96+j, vals[j], isbf);
        }
    }
    int gi = b_tasks[i];
    int g0 = b_tasks[blockIdx.x*256];
    if (gi != g0) s_nonuni = 1;
    __syncthreads();
    if (s_nonuni){
        for (int j=0;j<48;j++) atomicAdd(&pool_sums[gi*48+j], vals[j]);
        atomicAdd(&pool_cnt[gi], 1.f);
    } else {
        int lane = t & 63, wid = t >> 6;
        #pragma unroll
        for (int j=0;j<48;j++){
            float v = vals[j];
            v += __shfl_down(v, 32);
            v += __shfl_down(v, 16);
            v += __shfl_down(v, 8);
            v += __shfl_down(v, 4);
            v += __shfl_down(v, 2);
            v += __shfl_down(v, 1);
            if (lane==0) swave[wid*48+j] = v;
        }
        __syncthreads();
        if (t < 48){
            float s = swave[t] + swave[48+t] + swave[96+t] + swave[144+t];
            atomicAdd(&pool_sums[g0*48+t], s);
        }
        if (t == 0) atomicAdd(&pool_cnt[g0], 256.f);
    }
}

__global__ void finish_kernel(const float* __restrict__ sums, const float* __restrict__ cnt,
                              void* __restrict__ out, const int* __restrict__ flag)
{
    int t = threadIdx.x;
    if (t >= 768) return;
    int g = t/48, c = t - g*48;
    stf(out, g*96+48+c, fin(sums[g*48+c]/fmaxf(cnt[g],1.f)), *flag);
}

extern "C" void kernel_launch(void* const* d_in, const int* in_sizes, int n_in,
                              void* d_out, int out_size, void* d_ws, size_t ws_size,
                              hipStream_t stream)
{
    const void* x_tasks  = d_in[0];
    const void* x_data   = d_in[1];
    const void* stem_t_W = d_in[2];
    const void* stem_t_b = d_in[3];
    const void* stem_d_W = d_in[4];
    const void* stem_d_b = d_in[5];
    const void* ln_t_g   = d_in[6];
    const void* ln_t_b   = d_in[7];
    const void* ln_d_g   = d_in[8];
    const void* ln_d_b   = d_in[9];
    const void* dt_Wl    = d_in[10];
    const void* dt_Wr    = d_in[11];
    const void* dt_att   = d_in[12];
    const void* dt_res   = d_in[13];
    const void* dt_bias  = d_in[14];
    const void* tt_Wl    = d_in[15];
    const void* tt_Wr    = d_in[16];
    const void* tt_att   = d_in[17];
    const void* tt_res   = d_in[18];
    const void* tt_bias  = d_in[19];
    const void* ln1_g    = d_in[20];
    const void* ln1_b    = d_in[21];
    const void* ln2_g    = d_in[22];
    const void* ln2_b    = d_in[23];
    const int*  ei_dt    = (const int*)d_in[24];
    const int*  mask_dt  = (const int*)d_in[25];
    const int*  ei_tt    = (const int*)d_in[26];
    const int*  b_tasks  = (const int*)d_in[27];
    const int*  ptrg     = (const int*)d_in[28];

    char* w = (char*)d_ws;
    const size_t MB = 1ull<<20;
    float*    xt        = (float*)(w);              // 16 MB  [NT,16] fp32
    unsigned* xl_dt     = (unsigned*)(w + 16*MB);   // 16 MB  [ND,16] bf16x2-packed
    unsigned* xl_tt     = (unsigned*)(w + 32*MB);   // 16 MB  [NT,16] bf16x2-packed
    float*    agg       = (float*)(w + 48*MB);      // 32 MB  [NSLOT,16] fp32
    unsigned* ebuf      = (unsigned*)(w + 80*MB);   // 12 MB (NBKT*BCAP) + slack
    int*      bktCur    = (int*)  (w + 93*MB);      // 4 KB
    float*    pool_sums = (float*)(w + 93*MB + 8192);
    float*    pool_cnt  = (float*)(w + 93*MB + 12288);
    int*      flag      = (int*)  (w + 93*MB + 16384);

    detect_kernel<<<1, 256, 0, stream>>>((const unsigned*)x_tasks, flag);
    init_cursors_kernel<<<(NBKT+255)/256, 256, 0, stream>>>(bktCur);
    hipMemsetAsync(w + 93*MB + 8192, 0, 8192, stream);

    // stems
    stem_task_kernel<<<NT/256, 256, 0, stream>>>(x_tasks, stem_t_W, stem_t_b, ln_t_g, ln_t_b,
                                                 tt_Wl, xt, xl_tt, flag);
    stem_data_transform_kernel<<<ND/256, 256, 0, stream>>>(x_data, stem_d_W, stem_d_b,
                                                           ln_d_g, ln_d_b, dt_Wl, xl_dt, flag);

    // phase 1: coarse bucket scatter (both graphs)
    bucket_scatter_kernel<<<NBLK1, 256, 0, stream>>>(ei_dt, mask_dt, ei_tt, bktCur, ebuf);

    // phase 2: per-bucket LDS CSR + head-serial aggregation (both graphs)
    bucket_aggregate_kernel<<<NBKT, 256, 0, stream>>>(bktCur, ebuf, xt, xl_dt, xl_tt,
        dt_Wr, tt_Wr, dt_att, tt_att, agg, flag);

    // fuse + pool + output
    fuse_pool_kernel<<<NT/256, 256, 0, stream>>>(xt, agg, agg + (long)NT*16,
        dt_res, dt_bias, tt_res, tt_bias, ln1_g, ln1_b, ln2_g, ln2_b,
        b_tasks, ptrg, pool_sums, pool_cnt, d_out, flag);
    finish_kernel<<<1, 768, 0, stream>>>(pool_sums, pool_cnt, d_out, flag);
}

// Round 15
// 397.201 us; speedup vs baseline: 2.0687x; 1.0233x over previous
//
#include <hip/hip_runtime.h>
#include <hip/hip_bf16.h>

typedef __hip_bfloat16 bf16;

#define NT 262144
#define ND 262144
#define EDT 2097152
#define ETT 1048576
#define NSLOT (2*NT)            // [0,NT)=d2t dst slots, [NT,2NT)=tt dst slots
#define NE_TOT (EDT+ETT)        // 3145728
#define NBKT 1024               // coarse buckets, bucket = slot>>9
#define SPB 512                 // slots per bucket
#define BCAP 3072               // per-bucket ebuf capacity (mean ~2048)
#define CH 8192                 // edges per scatter block (32KB stage)
#define NBLK_SCAT (NE_TOT/CH)   // 384
#define NBLK_STEM (NT/256)      // 1024
#define NBLK_MEGA (2*NBLK_STEM + NBLK_SCAT)

// ---- dual-dtype load/store: isbf==1 -> bf16, else fp32 ----
__device__ __forceinline__ float ldf(const void* p, long i, int isbf){
    if (isbf) return __bfloat162float(((const bf16*)p)[i]);
    return ((const float*)p)[i];
}
__device__ __forceinline__ void stf(void* p, int i, float v, int isbf){
    if (isbf) ((bf16*)p)[i] = __float2bfloat16(v);
    else      ((float*)p)[i] = v;
}
__device__ __forceinline__ float fin(float x){
    return (x==x && x>-3e38f && x<3e38f) ? x : 0.f;
}
// ---- bf16x2 pack/unpack ----
__device__ __forceinline__ unsigned pk2(float a, float b){
    bf16 ha = __float2bfloat16(a), hb = __float2bfloat16(b);
    unsigned short ua = *(unsigned short*)&ha, ub = *(unsigned short*)&hb;
    return ((unsigned)ub<<16) | (unsigned)ua;
}
__device__ __forceinline__ float ulo(unsigned u){ return __uint_as_float(u<<16); }
__device__ __forceinline__ float uhi(unsigned u){ return __uint_as_float(u & 0xffff0000u); }

__device__ __forceinline__ float score8(uint4 u, const float* xr, const float* at){
    float s=0.f, m;
    m = ulo(u.x)+xr[0]; m = m>0.f?m:0.2f*m; s += m*at[0];
    m = uhi(u.x)+xr[1]; m = m>0.f?m:0.2f*m; s += m*at[1];
    m = ulo(u.y)+xr[2]; m = m>0.f?m:0.2f*m; s += m*at[2];
    m = uhi(u.y)+xr[3]; m = m>0.f?m:0.2f*m; s += m*at[3];
    m = ulo(u.z)+xr[4]; m = m>0.f?m:0.2f*m; s += m*at[4];
    m = uhi(u.z)+xr[5]; m = m>0.f?m:0.2f*m; s += m*at[5];
    m = ulo(u.w)+xr[6]; m = m>0.f?m:0.2f*m; s += m*at[6];
    m = uhi(u.w)+xr[7]; m = m>0.f?m:0.2f*m; s += m*at[7];
    return s;
}
__device__ __forceinline__ void acc8(uint4 u, float a, float* acc){
    acc[0] += a*ulo(u.x); acc[1] += a*uhi(u.x);
    acc[2] += a*ulo(u.y); acc[3] += a*uhi(u.y);
    acc[4] += a*ulo(u.z); acc[5] += a*uhi(u.z);
    acc[6] += a*ulo(u.w); acc[7] += a*uhi(u.w);
}

// ---------------- setup: detect dtype + init cursors + zero pool (1 block) ----------------
__global__ __launch_bounds__(256) void setup_kernel(
    const unsigned* __restrict__ raw, int* __restrict__ flag,
    int* __restrict__ bktCur, float* __restrict__ pool_sums, float* __restrict__ pool_cnt)
{
    __shared__ int cnt;
    int t = threadIdx.x;
    if (t==0) cnt = 0;
    __syncthreads();
    int c = 0;
    for (int i = t; i < 2048; i += 256){
        unsigned w = raw[i];
        unsigned e = (w >> 7) & 0xFFu;
        if (e >= 116u && e <= 134u) c++;
    }
    atomicAdd(&cnt, c);
    #pragma unroll
    for (int j=0;j<4;j++) bktCur[t + j*256] = (t + j*256)*BCAP;
    #pragma unroll
    for (int j=0;j<3;j++) pool_sums[t + j*256] = 0.f;
    if (t < 16) pool_cnt[t] = 0.f;
    __syncthreads();
    if (t==0) *flag = (cnt > 1024) ? 1 : 0;
}

// ---------------- mega kernel: both stems + bucket scatter (independent work) ----------------
// blocks [0,1024): task stem   [1024,2048): data stem   [2048,2432): scatter
union SmemMega {
    struct { float sW[192], sb[16], sg[16], sbt[16], sWl[512]; } st;   // task stem
    struct { float sW[80],  sb[16], sg[16], sbt[16], sWl[512]; } sd;   // data stem
    struct { int shc[NBKT], sloff[NBKT], slcur[NBKT], spart[256];
             unsigned stage[CH]; } sc;                                  // scatter (45KB, max)
};

__global__ __launch_bounds__(256) void mega_kernel(
    const void* __restrict__ x_tasks, const void* __restrict__ x_data,
    const void* __restrict__ stem_t_W, const void* __restrict__ stem_t_b,
    const void* __restrict__ ln_t_g, const void* __restrict__ ln_t_b,
    const void* __restrict__ stem_d_W, const void* __restrict__ stem_d_b,
    const void* __restrict__ ln_d_g, const void* __restrict__ ln_d_b,
    const void* __restrict__ tt_Wl, const void* __restrict__ dt_Wl,
    float* __restrict__ xt, unsigned* __restrict__ xl_tt, unsigned* __restrict__ xl_dt,
    const int* __restrict__ ei_dt, const int* __restrict__ mask_dt,
    const int* __restrict__ ei_tt,
    int* __restrict__ bktCur, unsigned* __restrict__ ebuf,
    const int* __restrict__ flag)
{
    __shared__ SmemMega sm;
    int t = threadIdx.x;
    int blk = blockIdx.x;

    if (blk < NBLK_STEM){
        // ---- task stem: xt + fused @tt_Wl -> xl_tt ----
        int isbf = *flag;
        if (t < 192) sm.st.sW[t] = ldf(stem_t_W, t, isbf);
        if (t < 16){ sm.st.sb[t]=ldf(stem_t_b,t,isbf); sm.st.sg[t]=ldf(ln_t_g,t,isbf); sm.st.sbt[t]=ldf(ln_t_b,t,isbf); }
        sm.st.sWl[t]     = ldf(tt_Wl, t,     isbf);
        sm.st.sWl[t+256] = ldf(tt_Wl, t+256, isbf);
        __syncthreads();
        long i = (long)blk*256 + t;
        float f[12];
        #pragma unroll
        for (int k=0;k<12;k++) f[k] = ldf(x_tasks, i*12+k, isbf);
        float h[16];
        #pragma unroll
        for (int c=0;c<16;c++){
            float a = sm.st.sb[c];
            #pragma unroll
            for (int k=0;k<12;k++) a += f[k]*sm.st.sW[k*16+c];
            h[c]=a;
        }
        float mu=0.f;
        #pragma unroll
        for (int c=0;c<16;c++) mu += h[c];
        mu *= (1.f/16.f);
        float var=0.f;
        #pragma unroll
        for (int c=0;c<16;c++){ float d=h[c]-mu; var += d*d; }
        var *= (1.f/16.f);
        float inv = rsqrtf(var + 1e-5f);
        float v[16];
        #pragma unroll
        for (int c=0;c<16;c++){
            float y = sm.st.sg[c]*(h[c]-mu)*inv + sm.st.sbt[c];
            v[c] = fin((y>0.f) ? y : 0.01f*y);
        }
        float4* xp = (float4*)(xt + i*16);
        #pragma unroll
        for (int q=0;q<4;q++) xp[q] = make_float4(v[q*4],v[q*4+1],v[q*4+2],v[q*4+3]);
        float o[32];
        #pragma unroll
        for (int c=0;c<32;c++) o[c]=0.f;
        #pragma unroll
        for (int k=0;k<16;k++){
            float xv=v[k];
            #pragma unroll
            for (int c=0;c<32;c++) o[c] += xv*sm.st.sWl[k*32+c];
        }
        #pragma unroll
        for (int c=0;c<32;c++) o[c] = fin(o[c]);
        uint4* op = (uint4*)(xl_tt + i*16);
        #pragma unroll
        for (int q=0;q<4;q++)
            op[q] = make_uint4(pk2(o[q*8],o[q*8+1]), pk2(o[q*8+2],o[q*8+3]),
                               pk2(o[q*8+4],o[q*8+5]), pk2(o[q*8+6],o[q*8+7]));
    } else if (blk < 2*NBLK_STEM){
        // ---- data stem: fused @dt_Wl -> xl_dt ----
        int isbf = *flag;
        if (t < 80) sm.sd.sW[t] = ldf(stem_d_W, t, isbf);
        if (t < 16){ sm.sd.sb[t]=ldf(stem_d_b,t,isbf); sm.sd.sg[t]=ldf(ln_d_g,t,isbf); sm.sd.sbt[t]=ldf(ln_d_b,t,isbf); }
        sm.sd.sWl[t]     = ldf(dt_Wl, t,     isbf);
        sm.sd.sWl[t+256] = ldf(dt_Wl, t+256, isbf);
        __syncthreads();
        long i = (long)(blk - NBLK_STEM)*256 + t;
        float f[5];
        #pragma unroll
        for (int k=0;k<5;k++) f[k] = ldf(x_data, i*5+k, isbf);
        float h[16];
        #pragma unroll
        for (int c=0;c<16;c++){
            float a = sm.sd.sb[c];
            #pragma unroll
            for (int k=0;k<5;k++) a += f[k]*sm.sd.sW[k*16+c];
            h[c]=a;
        }
        float mu=0.f;
        #pragma unroll
        for (int c=0;c<16;c++) mu += h[c];
        mu *= (1.f/16.f);
        float var=0.f;
        #pragma unroll
        for (int c=0;c<16;c++){ float d=h[c]-mu; var += d*d; }
        var *= (1.f/16.f);
        float inv = rsqrtf(var + 1e-5f);
        float v[16];
        #pragma unroll
        for (int c=0;c<16;c++){
            float y = sm.sd.sg[c]*(h[c]-mu)*inv + sm.sd.sbt[c];
            v[c] = (y>0.f) ? y : 0.01f*y;
        }
        float o[32];
        #pragma unroll
        for (int c=0;c<32;c++) o[c]=0.f;
        #pragma unroll
        for (int k=0;k<16;k++){
            float xv=v[k];
            #pragma unroll
            for (int c=0;c<32;c++) o[c] += xv*sm.sd.sWl[k*32+c];
        }
        #pragma unroll
        for (int c=0;c<32;c++) o[c] = fin(o[c]);
        uint4* op = (uint4*)(xl_dt + i*16);
        #pragma unroll
        for (int q=0;q<4;q++)
            op[q] = make_uint4(pk2(o[q*8],o[q*8+1]), pk2(o[q*8+2],o[q*8+3]),
                               pk2(o[q*8+4],o[q*8+5]), pk2(o[q*8+6],o[q*8+7]));
    } else {
        // ---- bucket scatter (LDS-staged), packed edge: src | dloc<<18 ----
        int bblk = blk - 2*NBLK_STEM;
        long e0 = (long)bblk * CH;
        for (int b=t; b<NBKT; b+=256) sm.sc.shc[b]=0;
        __syncthreads();
        for (int i=t; i<CH; i+=256){
            long e = e0 + i;
            int slot, keep;
            if (e < EDT){ keep = mask_dt[e]; slot = ei_dt[EDT+e]; }
            else { long e2 = e-EDT; keep = 1; slot = NT + ei_tt[ETT+e2]; }
            if (keep) atomicAdd(&sm.sc.shc[slot>>9], 1);
        }
        __syncthreads();
        int b4 = t*4;
        int a0=sm.sc.shc[b4], a1=sm.sc.shc[b4+1], a2=sm.sc.shc[b4+2], a3=sm.sc.shc[b4+3];
        int lsum = a0+a1+a2+a3;
        sm.sc.spart[t] = lsum;
        __syncthreads();
        for (int off=1; off<256; off<<=1){
            int x = sm.sc.spart[t];
            int add = (t>=off) ? sm.sc.spart[t-off] : 0;
            __syncthreads();
            sm.sc.spart[t] = x + add;
            __syncthreads();
        }
        int run = sm.sc.spart[t] - lsum;
        int totKept = sm.sc.spart[255];
        sm.sc.sloff[b4]=run;   sm.sc.slcur[b4]=run;   run+=a0;
        sm.sc.sloff[b4+1]=run; sm.sc.slcur[b4+1]=run; run+=a1;
        sm.sc.sloff[b4+2]=run; sm.sc.slcur[b4+2]=run; run+=a2;
        sm.sc.sloff[b4+3]=run; sm.sc.slcur[b4+3]=run;
        if (a0>0) sm.sc.shc[b4]   = atomicAdd(&bktCur[b4],   a0);
        if (a1>0) sm.sc.shc[b4+1] = atomicAdd(&bktCur[b4+1], a1);
        if (a2>0) sm.sc.shc[b4+2] = atomicAdd(&bktCur[b4+2], a2);
        if (a3>0) sm.sc.shc[b4+3] = atomicAdd(&bktCur[b4+3], a3);
        __syncthreads();
        for (int i=t; i<CH; i+=256){
            long e = e0 + i;
            int slot, keep, s;
            if (e < EDT){ keep = mask_dt[e]; s = ei_dt[e]; slot = ei_dt[EDT+e]; }
            else { long e2 = e-EDT; keep = 1; s = ei_tt[e2]; slot = NT + ei_tt[ETT+e2]; }
            if (keep){
                int b = slot>>9;
                int pos = atomicAdd(&sm.sc.slcur[b], 1);
                sm.sc.stage[pos] = (unsigned)s | ((unsigned)(slot & 511) << 18);
            }
        }
        __syncthreads();
        for (int i=t; i<totKept; i+=256){
            int lo=0, hi=NBKT-1;
            while (lo<hi){ int mid=(lo+hi+1)>>1; if (sm.sc.sloff[mid]<=i) lo=mid; else hi=mid-1; }
            ebuf[sm.sc.shc[lo] + (i - sm.sc.sloff[lo])] = sm.sc.stage[i];
        }
    }
}

// ---------------- phase 2: per-bucket LDS CSR + head-serial GAT aggregation ----------------
// (R14 proven best: 92 VGPR, head-serial passes, LDS spill for head-0 partial)
__global__ __launch_bounds__(256) void bucket_aggregate_kernel(
    const int* __restrict__ bktCur, const unsigned* __restrict__ ebuf,
    const float* __restrict__ xt,
    const unsigned* __restrict__ xl_dt, const unsigned* __restrict__ xl_tt,
    const void* __restrict__ dt_Wr, const void* __restrict__ tt_Wr,
    const void* __restrict__ dt_att, const void* __restrict__ tt_att,
    float* __restrict__ agg, const int* __restrict__ flag)
{
    __shared__ float sWr[512], satt[32];
    __shared__ int scnt[SPB], soff[SPB], scur[SPB], spart[256];
    __shared__ unsigned slist[BCAP];
    __shared__ float sspill[256*17];
    int t = threadIdx.x;
    int b = blockIdx.x;
    int which = (b >= NBKT/2);
    int isbf = *flag;
    const void* Wr  = which ? tt_Wr  : dt_Wr;
    const void* att = which ? tt_att : dt_att;
    sWr[t]     = ldf(Wr, t,     isbf);
    sWr[t+256] = ldf(Wr, t+256, isbf);
    if (t < 32) satt[t] = ldf(att, t, isbf);
    scnt[t] = 0; scnt[t+256] = 0;
    __syncthreads();
    int base = b*BCAP;
    int ecnt = bktCur[b] - base;
    if (ecnt > BCAP) ecnt = BCAP;
    if (ecnt < 0) ecnt = 0;
    for (int i=t; i<ecnt; i+=256)
        atomicAdd(&scnt[ebuf[base+i] >> 18], 1);
    __syncthreads();
    int c0 = scnt[2*t], c1 = scnt[2*t+1];
    int ls = c0 + c1;
    spart[t] = ls;
    __syncthreads();
    for (int off=1; off<256; off<<=1){
        int x = spart[t];
        int add = (t>=off) ? spart[t-off] : 0;
        __syncthreads();
        spart[t] = x + add;
        __syncthreads();
    }
    int run = spart[t] - ls;
    soff[2*t] = run; scur[2*t] = run;
    soff[2*t+1] = run + c0; scur[2*t+1] = run + c0;
    __syncthreads();
    for (int i=t; i<ecnt; i+=256){
        unsigned p = ebuf[base+i];
        int pos = atomicAdd(&scur[p >> 18], 1);
        slist[pos] = p & 0x3FFFFu;
    }
    __syncthreads();
    const unsigned* xl = which ? xl_tt : xl_dt;
    #pragma unroll 1
    for (int half=0; half<2; half++){
        int dloc = t + half*256;
        long slot = (long)b*SPB + dloc;
        long d = which ? slot - NT : slot;
        int e0 = soff[dloc], e1 = scur[dloc];
        #pragma unroll 1
        for (int head=0; head<2; head++){
            const float4* xp = (const float4*)(xt + d*16);
            float4 x0=xp[0], x1=xp[1], x2=xp[2], x3=xp[3];
            float xtv[16] = {x0.x,x0.y,x0.z,x0.w, x1.x,x1.y,x1.z,x1.w,
                             x2.x,x2.y,x2.z,x2.w, x3.x,x3.y,x3.z,x3.w};
            float xr[16];
            #pragma unroll
            for (int c=0;c<16;c++) xr[c]=0.f;
            #pragma unroll
            for (int k=0;k<16;k++){
                float xv=xtv[k];
                #pragma unroll
                for (int c=0;c<16;c++) xr[c] += xv*sWr[k*32 + head*16 + c];
            }
            const float* at = satt + head*16;
            float acc[16];
            #pragma unroll
            for (int c=0;c<16;c++) acc[c]=0.f;
            float den=0.f;
            for (int e=e0; e<e1; e++){
                long s = slist[e];
                const uint4* p = (const uint4*)(xl + s*16 + head*8);
                uint4 u0 = p[0], u1 = p[1];
                float sc = score8(u0, xr, at) + score8(u1, xr+8, at+8);
                float a = expf(fminf(fin(sc), 60.f));
                den += a;
                acc8(u0, a, acc); acc8(u1, a, acc+8);
            }
            float id = 1.f/fmaxf(den, 1e-16f);
            if (head==0){
                #pragma unroll
                for (int c=0;c<16;c++) sspill[t*17+c] = acc[c]*id;
            } else {
                float4* op = (float4*)(agg + slot*16);
                #pragma unroll
                for (int q=0;q<4;q++){
                    float v[4];
                    #pragma unroll
                    for (int j=0;j<4;j++)
                        v[j] = fin(0.5f*(sspill[t*17+q*4+j] + acc[q*4+j]*id));
                    op[q] = make_float4(v[0],v[1],v[2],v[3]);
                }
            }
        }
    }
}

__device__ __forceinline__ void ln_act16(const float* v, const float* g, const float* b, float* o){
    float mu=0.f;
    #pragma unroll
    for (int c=0;c<16;c++) mu += v[c];
    mu *= (1.f/16.f);
    float var=0.f;
    #pragma unroll
    for (int c=0;c<16;c++){ float d=v[c]-mu; var += d*d; }
    var *= (1.f/16.f);
    float inv = rsqrtf(var + 1e-5f);
    #pragma unroll
    for (int c=0;c<16;c++){
        float y = g[c]*(v[c]-mu)*inv + b[c];
        o[c] = (y>0.f) ? y : 0.01f*y;
    }
}

// ---------------- fuse + pooling (wave-shuffle reduction) ----------------
__global__ __launch_bounds__(256) void fuse_pool_kernel(
    const float* __restrict__ xt,
    const float* __restrict__ agg_dt, const float* __restrict__ agg_tt,
    const void* __restrict__ dt_res, const void* __restrict__ dt_bias,
    const void* __restrict__ tt_res, const void* __restrict__ tt_bias,
    const void* __restrict__ ln1g, const void* __restrict__ ln1b,
    const void* __restrict__ ln2g, const void* __restrict__ ln2b,
    const int* __restrict__ b_tasks, const int* __restrict__ ptrg,
    float* __restrict__ pool_sums, float* __restrict__ pool_cnt,
    void* __restrict__ out, const int* __restrict__ flag)
{
    int isbf = *flag;
    __shared__ float sdt[256], stt[256], sdb[16], stb[16], s1g[16], s1b[16], s2g[16], s2b[16];
    __shared__ float swave[4*48];
    __shared__ int sptr[16];
    __shared__ int s_nonuni;
    int t = threadIdx.x;
    sdt[t] = ldf(dt_res, t, isbf);
    stt[t] = ldf(tt_res, t, isbf);
    if (t < 16){
        sdb[t]=ldf(dt_bias,t,isbf); stb[t]=ldf(tt_bias,t,isbf);
        s1g[t]=ldf(ln1g,t,isbf); s1b[t]=ldf(ln1b,t,isbf);
        s2g[t]=ldf(ln2g,t,isbf); s2b[t]=ldf(ln2b,t,isbf);
        sptr[t]=ptrg[t];
    }
    if (t==0) s_nonuni = 0;
    __syncthreads();
    long i = blockIdx.x*256 + t;
    const float4* xp = (const float4*)(xt + i*16);
    float4 x0=xp[0], x1=xp[1], x2=xp[2], x3=xp[3];
    float vals[48];
    float* xv   = vals;
    float* tupd = vals+16;
    float* dupd = vals+32;
    xv[0]=x0.x; xv[1]=x0.y; xv[2]=x0.z; xv[3]=x0.w;
    xv[4]=x1.x; xv[5]=x1.y; xv[6]=x1.z; xv[7]=x1.w;
    xv[8]=x2.x; xv[9]=x2.y; xv[10]=x2.z; xv[11]=x2.w;
    xv[12]=x3.x; xv[13]=x3.y; xv[14]=x3.z; xv[15]=x3.w;
    {
        const float* ag = agg_dt + i*16;
        float v[16];
        #pragma unroll
        for (int c=0;c<16;c++){
            float r = sdb[c];
            #pragma unroll
            for (int k=0;k<16;k++) r += xv[k]*sdt[k*16+c];
            v[c] = fin(ag[c] + r);
        }
        ln_act16(v, s1g, s1b, dupd);
    }
    {
        const float* ag = agg_tt + i*16;
        float v[16];
        #pragma unroll
        for (int c=0;c<16;c++){
            float r = stb[c];
            #pragma unroll
            for (int k=0;k<16;k++) r += xv[k]*stt[k*16+c];
            v[c] = fin(ag[c] + r);
        }
        ln_act16(v, s2g, s2b, tupd);
    }
    #pragma unroll
    for (int j=0;j<48;j++) vals[j] = fin(vals[j]);
    #pragma unroll
    for (int g=0; g<16; g++){
        if (i == sptr[g]){
            for (int j=0;j<48;j++) stf(out, g*96+j, vals[j], isbf);
        }
    }
    int gi = b_tasks[i];
    int g0 = b_tasks[blockIdx.x*256];
    if (gi != g0) s_nonuni = 1;
    __syncthreads();
    if (s_nonuni){
        for (int j=0;j<48;j++) atomicAdd(&pool_sums[gi*48+j], vals[j]);
        atomicAdd(&pool_cnt[gi], 1.f);
    } else {
        int lane = t & 63, wid = t >> 6;
        #pragma unroll
        for (int j=0;j<48;j++){
            float v = vals[j];
            v += __shfl_down(v, 32);
            v += __shfl_down(v, 16);
            v += __shfl_down(v, 8);
            v += __shfl_down(v, 4);
            v += __shfl_down(v, 2);
            v += __shfl_down(v, 1);
            if (lane==0) swave[wid*48+j] = v;
        }
        __syncthreads();
        if (t < 48){
            float s = swave[t] + swave[48+t] + swave[96+t] + swave[144+t];
            atomicAdd(&pool_sums[g0*48+t], s);
        }
        if (t == 0) atomicAdd(&pool_cnt[g0], 256.f);
    }
}

__global__ void finish_kernel(const float* __restrict__ sums, const float* __restrict__ cnt,
                              void* __restrict__ out, const int* __restrict__ flag)
{
    int t = threadIdx.x;
    if (t >= 768) return;
    int g = t/48, c = t - g*48;
    stf(out, g*96+48+c, fin(sums[g*48+c]/fmaxf(cnt[g],1.f)), *flag);
}

extern "C" void kernel_launch(void* const* d_in, const int* in_sizes, int n_in,
                              void* d_out, int out_size, void* d_ws, size_t ws_size,
                              hipStream_t stream)
{
    const void* x_tasks  = d_in[0];
    const void* x_data   = d_in[1];
    const void* stem_t_W = d_in[2];
    const void* stem_t_b = d_in[3];
    const void* stem_d_W = d_in[4];
    const void* stem_d_b = d_in[5];
    const void* ln_t_g   = d_in[6];
    const void* ln_t_b   = d_in[7];
    const void* ln_d_g   = d_in[8];
    const void* ln_d_b   = d_in[9];
    const void* dt_Wl    = d_in[10];
    const void* dt_Wr    = d_in[11];
    const void* dt_att   = d_in[12];
    const void* dt_res   = d_in[13];
    const void* dt_bias  = d_in[14];
    const void* tt_Wl    = d_in[15];
    const void* tt_Wr    = d_in[16];
    const void* tt_att   = d_in[17];
    const void* tt_res   = d_in[18];
    const void* tt_bias  = d_in[19];
    const void* ln1_g    = d_in[20];
    const void* ln1_b    = d_in[21];
    const void* ln2_g    = d_in[22];
    const void* ln2_b    = d_in[23];
    const int*  ei_dt    = (const int*)d_in[24];
    const int*  mask_dt  = (const int*)d_in[25];
    const int*  ei_tt    = (const int*)d_in[26];
    const int*  b_tasks  = (const int*)d_in[27];
    const int*  ptrg     = (const int*)d_in[28];

    char* w = (char*)d_ws;
    const size_t MB = 1ull<<20;
    float*    xt        = (float*)(w);              // 16 MB  [NT,16] fp32
    unsigned* xl_dt     = (unsigned*)(w + 16*MB);   // 16 MB  [ND,16] bf16x2-packed
    unsigned* xl_tt     = (unsigned*)(w + 32*MB);   // 16 MB  [NT,16] bf16x2-packed
    float*    agg       = (float*)(w + 48*MB);      // 32 MB  [NSLOT,16] fp32
    unsigned* ebuf      = (unsigned*)(w + 80*MB);   // 12 MB (NBKT*BCAP) + slack
    int*      bktCur    = (int*)  (w + 93*MB);      // 4 KB
    float*    pool_sums = (float*)(w + 93*MB + 8192);
    float*    pool_cnt  = (float*)(w + 93*MB + 12288);
    int*      flag      = (int*)  (w + 93*MB + 16384);

    // setup: detect dtype + init bucket cursors + zero pool accumulators
    setup_kernel<<<1, 256, 0, stream>>>((const unsigned*)x_tasks, flag, bktCur, pool_sums, pool_cnt);

    // mega: task stem + data stem + bucket scatter (mutually independent)
    mega_kernel<<<NBLK_MEGA, 256, 0, stream>>>(
        x_tasks, x_data, stem_t_W, stem_t_b, ln_t_g, ln_t_b,
        stem_d_W, stem_d_b, ln_d_g, ln_d_b, tt_Wl, dt_Wl,
        xt, xl_tt, xl_dt, ei_dt, mask_dt, ei_tt, bktCur, ebuf, flag);

    // per-bucket LDS CSR + head-serial aggregation (both graphs)
    bucket_aggregate_kernel<<<NBKT, 256, 0, stream>>>(bktCur, ebuf, xt, xl_dt, xl_tt,
        dt_Wr, tt_Wr, dt_att, tt_att, agg, flag);

    // fuse + pool + output
    fuse_pool_kernel<<<NT/256, 256, 0, stream>>>(xt, agg, agg + (long)NT*16,
        dt_res, dt_bias, tt_res, tt_bias, ln1_g, ln1_b, ln2_g, ln2_b,
        b_tasks, ptrg, pool_sums, pool_cnt, d_out, flag);
    finish_kernel<<<1, 768, 0, stream>>>(pool_sums, pool_cnt, d_out, flag);
}

// Round 16
// 377.125 us; speedup vs baseline: 2.1788x; 1.0532x over previous
//
#include <hip/hip_runtime.h>
#include <hip/hip_bf16.h>

typedef __hip_bfloat16 bf16;

#define NT 262144
#define ND 262144
#define EDT 2097152
#define ETT 1048576
#define NSLOT (2*NT)            // [0,NT)=d2t dst slots, [NT,2NT)=tt dst slots
#define NE_TOT (EDT+ETT)        // 3145728
#define NBKT 1024               // coarse buckets, bucket = slot>>9
#define SPB 512                 // slots per bucket
#define BCAP 3072               // per-bucket ebuf capacity (mean ~2048)
#define CH 8192                 // edges per scatter block (32KB stage)
#define NBLK_SCAT (NE_TOT/CH)   // 384
#define NBLK_STEM (NT/256)      // 1024
#define NBLK_MEGA (2*NBLK_STEM + NBLK_SCAT)

// ---- dual-dtype load/store: isbf==1 -> bf16, else fp32 ----
__device__ __forceinline__ float ldf(const void* p, long i, int isbf){
    if (isbf) return __bfloat162float(((const bf16*)p)[i]);
    return ((const float*)p)[i];
}
__device__ __forceinline__ void stf(void* p, int i, float v, int isbf){
    if (isbf) ((bf16*)p)[i] = __float2bfloat16(v);
    else      ((float*)p)[i] = v;
}
__device__ __forceinline__ float fin(float x){
    return (x==x && x>-3e38f && x<3e38f) ? x : 0.f;
}
// ---- bf16x2 pack/unpack ----
__device__ __forceinline__ unsigned pk2(float a, float b){
    bf16 ha = __float2bfloat16(a), hb = __float2bfloat16(b);
    unsigned short ua = *(unsigned short*)&ha, ub = *(unsigned short*)&hb;
    return ((unsigned)ub<<16) | (unsigned)ua;
}
__device__ __forceinline__ float ulo(unsigned u){ return __uint_as_float(u<<16); }
__device__ __forceinline__ float uhi(unsigned u){ return __uint_as_float(u & 0xffff0000u); }

__device__ __forceinline__ float score8(uint4 u, const float* xr, const float* at){
    float s=0.f, m;
    m = ulo(u.x)+xr[0]; m = m>0.f?m:0.2f*m; s += m*at[0];
    m = uhi(u.x)+xr[1]; m = m>0.f?m:0.2f*m; s += m*at[1];
    m = ulo(u.y)+xr[2]; m = m>0.f?m:0.2f*m; s += m*at[2];
    m = uhi(u.y)+xr[3]; m = m>0.f?m:0.2f*m; s += m*at[3];
    m = ulo(u.z)+xr[4]; m = m>0.f?m:0.2f*m; s += m*at[4];
    m = uhi(u.z)+xr[5]; m = m>0.f?m:0.2f*m; s += m*at[5];
    m = ulo(u.w)+xr[6]; m = m>0.f?m:0.2f*m; s += m*at[6];
    m = uhi(u.w)+xr[7]; m = m>0.f?m:0.2f*m; s += m*at[7];
    return s;
}
__device__ __forceinline__ void acc8(uint4 u, float a, float* acc){
    acc[0] += a*ulo(u.x); acc[1] += a*uhi(u.x);
    acc[2] += a*ulo(u.y); acc[3] += a*uhi(u.y);
    acc[4] += a*ulo(u.z); acc[5] += a*uhi(u.z);
    acc[6] += a*ulo(u.w); acc[7] += a*uhi(u.w);
}

// ---------------- setup: detect dtype + init cursors + zero pool/done (1 block) ----------------
__global__ __launch_bounds__(256) void setup_kernel(
    const unsigned* __restrict__ raw, int* __restrict__ flag,
    int* __restrict__ bktCur, float* __restrict__ pool_sums, float* __restrict__ pool_cnt,
    int* __restrict__ done)
{
    __shared__ int cnt;
    int t = threadIdx.x;
    if (t==0) cnt = 0;
    __syncthreads();
    int c = 0;
    for (int i = t; i < 2048; i += 256){
        unsigned w = raw[i];
        unsigned e = (w >> 7) & 0xFFu;
        if (e >= 116u && e <= 134u) c++;
    }
    atomicAdd(&cnt, c);
    #pragma unroll
    for (int j=0;j<4;j++) bktCur[t + j*256] = (t + j*256)*BCAP;
    #pragma unroll
    for (int j=0;j<3;j++) pool_sums[t + j*256] = 0.f;
    if (t < 16) pool_cnt[t] = 0.f;
    if (t == 0) *done = 0;
    __syncthreads();
    if (t==0) *flag = (cnt > 1024) ? 1 : 0;
}

// ---------------- mega kernel: scatter first, then both stems ----------------
// blocks [0,384): scatter   [384,1408): task stem   [1408,2432): data stem
union SmemMega {
    struct { float sW[192], sb[16], sg[16], sbt[16], sWl[512]; } st;   // task stem
    struct { float sW[80],  sb[16], sg[16], sbt[16], sWl[512]; } sd;   // data stem
    struct { int shc[NBKT], sloff[NBKT], slcur[NBKT], spart[256];
             unsigned stage[CH]; } sc;                                  // scatter (45KB, max)
};

__global__ __launch_bounds__(256) void mega_kernel(
    const void* __restrict__ x_tasks, const void* __restrict__ x_data,
    const void* __restrict__ stem_t_W, const void* __restrict__ stem_t_b,
    const void* __restrict__ ln_t_g, const void* __restrict__ ln_t_b,
    const void* __restrict__ stem_d_W, const void* __restrict__ stem_d_b,
    const void* __restrict__ ln_d_g, const void* __restrict__ ln_d_b,
    const void* __restrict__ tt_Wl, const void* __restrict__ dt_Wl,
    float* __restrict__ xt, unsigned* __restrict__ xl_tt, unsigned* __restrict__ xl_dt,
    const int* __restrict__ ei_dt, const int* __restrict__ mask_dt,
    const int* __restrict__ ei_tt,
    int* __restrict__ bktCur, unsigned* __restrict__ ebuf,
    const int* __restrict__ flag)
{
    __shared__ SmemMega sm;
    int t = threadIdx.x;
    int blk = blockIdx.x;

    if (blk < NBLK_SCAT){
        // ---- bucket scatter (LDS-staged), packed edge: src | dloc<<18 ----
        long e0 = (long)blk * CH;
        for (int b=t; b<NBKT; b+=256) sm.sc.shc[b]=0;
        __syncthreads();
        for (int i=t; i<CH; i+=256){
            long e = e0 + i;
            int slot, keep;
            if (e < EDT){ keep = mask_dt[e]; slot = ei_dt[EDT+e]; }
            else { long e2 = e-EDT; keep = 1; slot = NT + ei_tt[ETT+e2]; }
            if (keep) atomicAdd(&sm.sc.shc[slot>>9], 1);
        }
        __syncthreads();
        int b4 = t*4;
        int a0=sm.sc.shc[b4], a1=sm.sc.shc[b4+1], a2=sm.sc.shc[b4+2], a3=sm.sc.shc[b4+3];
        int lsum = a0+a1+a2+a3;
        sm.sc.spart[t] = lsum;
        __syncthreads();
        for (int off=1; off<256; off<<=1){
            int x = sm.sc.spart[t];
            int add = (t>=off) ? sm.sc.spart[t-off] : 0;
            __syncthreads();
            sm.sc.spart[t] = x + add;
            __syncthreads();
        }
        int run = sm.sc.spart[t] - lsum;
        int totKept = sm.sc.spart[255];
        sm.sc.sloff[b4]=run;   sm.sc.slcur[b4]=run;   run+=a0;
        sm.sc.sloff[b4+1]=run; sm.sc.slcur[b4+1]=run; run+=a1;
        sm.sc.sloff[b4+2]=run; sm.sc.slcur[b4+2]=run; run+=a2;
        sm.sc.sloff[b4+3]=run; sm.sc.slcur[b4+3]=run;
        if (a0>0) sm.sc.shc[b4]   = atomicAdd(&bktCur[b4],   a0);
        if (a1>0) sm.sc.shc[b4+1] = atomicAdd(&bktCur[b4+1], a1);
        if (a2>0) sm.sc.shc[b4+2] = atomicAdd(&bktCur[b4+2], a2);
        if (a3>0) sm.sc.shc[b4+3] = atomicAdd(&bktCur[b4+3], a3);
        __syncthreads();
        for (int i=t; i<CH; i+=256){
            long e = e0 + i;
            int slot, keep, s;
            if (e < EDT){ keep = mask_dt[e]; s = ei_dt[e]; slot = ei_dt[EDT+e]; }
            else { long e2 = e-EDT; keep = 1; s = ei_tt[e2]; slot = NT + ei_tt[ETT+e2]; }
            if (keep){
                int b = slot>>9;
                int pos = atomicAdd(&sm.sc.slcur[b], 1);
                sm.sc.stage[pos] = (unsigned)s | ((unsigned)(slot & 511) << 18);
            }
        }
        __syncthreads();
        for (int i=t; i<totKept; i+=256){
            int lo=0, hi=NBKT-1;
            while (lo<hi){ int mid=(lo+hi+1)>>1; if (sm.sc.sloff[mid]<=i) lo=mid; else hi=mid-1; }
            ebuf[sm.sc.shc[lo] + (i - sm.sc.sloff[lo])] = sm.sc.stage[i];
        }
    } else if (blk < NBLK_SCAT + NBLK_STEM){
        // ---- task stem: xt + fused @tt_Wl -> xl_tt ----
        int isbf = *flag;
        if (t < 192) sm.st.sW[t] = ldf(stem_t_W, t, isbf);
        if (t < 16){ sm.st.sb[t]=ldf(stem_t_b,t,isbf); sm.st.sg[t]=ldf(ln_t_g,t,isbf); sm.st.sbt[t]=ldf(ln_t_b,t,isbf); }
        sm.st.sWl[t]     = ldf(tt_Wl, t,     isbf);
        sm.st.sWl[t+256] = ldf(tt_Wl, t+256, isbf);
        __syncthreads();
        long i = (long)(blk - NBLK_SCAT)*256 + t;
        float f[12];
        #pragma unroll
        for (int k=0;k<12;k++) f[k] = ldf(x_tasks, i*12+k, isbf);
        float h[16];
        #pragma unroll
        for (int c=0;c<16;c++){
            float a = sm.st.sb[c];
            #pragma unroll
            for (int k=0;k<12;k++) a += f[k]*sm.st.sW[k*16+c];
            h[c]=a;
        }
        float mu=0.f;
        #pragma unroll
        for (int c=0;c<16;c++) mu += h[c];
        mu *= (1.f/16.f);
        float var=0.f;
        #pragma unroll
        for (int c=0;c<16;c++){ float d=h[c]-mu; var += d*d; }
        var *= (1.f/16.f);
        float inv = rsqrtf(var + 1e-5f);
        float v[16];
        #pragma unroll
        for (int c=0;c<16;c++){
            float y = sm.st.sg[c]*(h[c]-mu)*inv + sm.st.sbt[c];
            v[c] = fin((y>0.f) ? y : 0.01f*y);
        }
        float4* xp = (float4*)(xt + i*16);
        #pragma unroll
        for (int q=0;q<4;q++) xp[q] = make_float4(v[q*4],v[q*4+1],v[q*4+2],v[q*4+3]);
        float o[32];
        #pragma unroll
        for (int c=0;c<32;c++) o[c]=0.f;
        #pragma unroll
        for (int k=0;k<16;k++){
            float xv=v[k];
            #pragma unroll
            for (int c=0;c<32;c++) o[c] += xv*sm.st.sWl[k*32+c];
        }
        #pragma unroll
        for (int c=0;c<32;c++) o[c] = fin(o[c]);
        uint4* op = (uint4*)(xl_tt + i*16);
        #pragma unroll
        for (int q=0;q<4;q++)
            op[q] = make_uint4(pk2(o[q*8],o[q*8+1]), pk2(o[q*8+2],o[q*8+3]),
                               pk2(o[q*8+4],o[q*8+5]), pk2(o[q*8+6],o[q*8+7]));
    } else {
        // ---- data stem: fused @dt_Wl -> xl_dt ----
        int isbf = *flag;
        if (t < 80) sm.sd.sW[t] = ldf(stem_d_W, t, isbf);
        if (t < 16){ sm.sd.sb[t]=ldf(stem_d_b,t,isbf); sm.sd.sg[t]=ldf(ln_d_g,t,isbf); sm.sd.sbt[t]=ldf(ln_d_b,t,isbf); }
        sm.sd.sWl[t]     = ldf(dt_Wl, t,     isbf);
        sm.sd.sWl[t+256] = ldf(dt_Wl, t+256, isbf);
        __syncthreads();
        long i = (long)(blk - NBLK_SCAT - NBLK_STEM)*256 + t;
        float f[5];
        #pragma unroll
        for (int k=0;k<5;k++) f[k] = ldf(x_data, i*5+k, isbf);
        float h[16];
        #pragma unroll
        for (int c=0;c<16;c++){
            float a = sm.sd.sb[c];
            #pragma unroll
            for (int k=0;k<5;k++) a += f[k]*sm.sd.sW[k*16+c];
            h[c]=a;
        }
        float mu=0.f;
        #pragma unroll
        for (int c=0;c<16;c++) mu += h[c];
        mu *= (1.f/16.f);
        float var=0.f;
        #pragma unroll
        for (int c=0;c<16;c++){ float d=h[c]-mu; var += d*d; }
        var *= (1.f/16.f);
        float inv = rsqrtf(var + 1e-5f);
        float v[16];
        #pragma unroll
        for (int c=0;c<16;c++){
            float y = sm.sd.sg[c]*(h[c]-mu)*inv + sm.sd.sbt[c];
            v[c] = (y>0.f) ? y : 0.01f*y;
        }
        float o[32];
        #pragma unroll
        for (int c=0;c<32;c++) o[c]=0.f;
        #pragma unroll
        for (int k=0;k<16;k++){
            float xv=v[k];
            #pragma unroll
            for (int c=0;c<32;c++) o[c] += xv*sm.sd.sWl[k*32+c];
        }
        #pragma unroll
        for (int c=0;c<32;c++) o[c] = fin(o[c]);
        uint4* op = (uint4*)(xl_dt + i*16);
        #pragma unroll
        for (int q=0;q<4;q++)
            op[q] = make_uint4(pk2(o[q*8],o[q*8+1]), pk2(o[q*8+2],o[q*8+3]),
                               pk2(o[q*8+4],o[q*8+5]), pk2(o[q*8+6],o[q*8+7]));
    }
}

// ---------------- phase 2: per-bucket LDS CSR + head-serial GAT aggregation ----------------
__global__ __launch_bounds__(256) void bucket_aggregate_kernel(
    const int* __restrict__ bktCur, const unsigned* __restrict__ ebuf,
    const float* __restrict__ xt,
    const unsigned* __restrict__ xl_dt, const unsigned* __restrict__ xl_tt,
    const void* __restrict__ dt_Wr, const void* __restrict__ tt_Wr,
    const void* __restrict__ dt_att, const void* __restrict__ tt_att,
    float* __restrict__ agg, const int* __restrict__ flag)
{
    __shared__ float sWr[512], satt[32];
    __shared__ int scnt[SPB], soff[SPB], scur[SPB], spart[256];
    __shared__ unsigned slist[BCAP];
    __shared__ float sspill[256*17];
    int t = threadIdx.x;
    int b = blockIdx.x;
    int which = (b >= NBKT/2);
    int isbf = *flag;
    const void* Wr  = which ? tt_Wr  : dt_Wr;
    const void* att = which ? tt_att : dt_att;
    sWr[t]     = ldf(Wr, t,     isbf);
    sWr[t+256] = ldf(Wr, t+256, isbf);
    if (t < 32) satt[t] = ldf(att, t, isbf);
    scnt[t] = 0; scnt[t+256] = 0;
    __syncthreads();
    int base = b*BCAP;
    int ecnt = bktCur[b] - base;
    if (ecnt > BCAP) ecnt = BCAP;
    if (ecnt < 0) ecnt = 0;
    for (int i=t; i<ecnt; i+=256)
        atomicAdd(&scnt[ebuf[base+i] >> 18], 1);
    __syncthreads();
    int c0 = scnt[2*t], c1 = scnt[2*t+1];
    int ls = c0 + c1;
    spart[t] = ls;
    __syncthreads();
    for (int off=1; off<256; off<<=1){
        int x = spart[t];
        int add = (t>=off) ? spart[t-off] : 0;
        __syncthreads();
        spart[t] = x + add;
        __syncthreads();
    }
    int run = spart[t] - ls;
    soff[2*t] = run; scur[2*t] = run;
    soff[2*t+1] = run + c0; scur[2*t+1] = run + c0;
    __syncthreads();
    for (int i=t; i<ecnt; i+=256){
        unsigned p = ebuf[base+i];
        int pos = atomicAdd(&scur[p >> 18], 1);
        slist[pos] = p & 0x3FFFFu;
    }
    __syncthreads();
    const unsigned* xl = which ? xl_tt : xl_dt;
    #pragma unroll 1
    for (int half=0; half<2; half++){
        int dloc = t + half*256;
        long slot = (long)b*SPB + dloc;
        long d = which ? slot - NT : slot;
        int e0 = soff[dloc], e1 = scur[dloc];
        #pragma unroll 1
        for (int head=0; head<2; head++){
            const float4* xp = (const float4*)(xt + d*16);
            float4 x0=xp[0], x1=xp[1], x2=xp[2], x3=xp[3];
            float xtv[16] = {x0.x,x0.y,x0.z,x0.w, x1.x,x1.y,x1.z,x1.w,
                             x2.x,x2.y,x2.z,x2.w, x3.x,x3.y,x3.z,x3.w};
            float xr[16];
            #pragma unroll
            for (int c=0;c<16;c++) xr[c]=0.f;
            #pragma unroll
            for (int k=0;k<16;k++){
                float xv=xtv[k];
                #pragma unroll
                for (int c=0;c<16;c++) xr[c] += xv*sWr[k*32 + head*16 + c];
            }
            const float* at = satt + head*16;
            float acc[16];
            #pragma unroll
            for (int c=0;c<16;c++) acc[c]=0.f;
            float den=0.f;
            for (int e=e0; e<e1; e++){
                long s = slist[e];
                const uint4* p = (const uint4*)(xl + s*16 + head*8);
                uint4 u0 = p[0], u1 = p[1];
                float sc = score8(u0, xr, at) + score8(u1, xr+8, at+8);
                float a = expf(fminf(fin(sc), 60.f));
                den += a;
                acc8(u0, a, acc); acc8(u1, a, acc+8);
            }
            float id = 1.f/fmaxf(den, 1e-16f);
            if (head==0){
                #pragma unroll
                for (int c=0;c<16;c++) sspill[t*17+c] = acc[c]*id;
            } else {
                float4* op = (float4*)(agg + slot*16);
                #pragma unroll
                for (int q=0;q<4;q++){
                    float v[4];
                    #pragma unroll
                    for (int j=0;j<4;j++)
                        v[j] = fin(0.5f*(sspill[t*17+q*4+j] + acc[q*4+j]*id));
                    op[q] = make_float4(v[0],v[1],v[2],v[3]);
                }
            }
        }
    }
}

__device__ __forceinline__ void ln_act16(const float* v, const float* g, const float* b, float* o){
    float mu=0.f;
    #pragma unroll
    for (int c=0;c<16;c++) mu += v[c];
    mu *= (1.f/16.f);
    float var=0.f;
    #pragma unroll
    for (int c=0;c<16;c++){ float d=v[c]-mu; var += d*d; }
    var *= (1.f/16.f);
    float inv = rsqrtf(var + 1e-5f);
    #pragma unroll
    for (int c=0;c<16;c++){
        float y = g[c]*(v[c]-mu)*inv + b[c];
        o[c] = (y>0.f) ? y : 0.01f*y;
    }
}

// ---------------- fuse + pooling + last-block finish ----------------
__global__ __launch_bounds__(256) void fuse_pool_kernel(
    const float* __restrict__ xt,
    const float* __restrict__ agg_dt, const float* __restrict__ agg_tt,
    const void* __restrict__ dt_res, const void* __restrict__ dt_bias,
    const void* __restrict__ tt_res, const void* __restrict__ tt_bias,
    const void* __restrict__ ln1g, const void* __restrict__ ln1b,
    const void* __restrict__ ln2g, const void* __restrict__ ln2b,
    const int* __restrict__ b_tasks, const int* __restrict__ ptrg,
    float* __restrict__ pool_sums, float* __restrict__ pool_cnt,
    int* __restrict__ done,
    void* __restrict__ out, const int* __restrict__ flag)
{
    int isbf = *flag;
    __shared__ float sdt[256], stt[256], sdb[16], stb[16], s1g[16], s1b[16], s2g[16], s2b[16];
    __shared__ float swave[4*48];
    __shared__ int sptr[16];
    __shared__ int s_nonuni;
    __shared__ int s_last;
    int t = threadIdx.x;
    sdt[t] = ldf(dt_res, t, isbf);
    stt[t] = ldf(tt_res, t, isbf);
    if (t < 16){
        sdb[t]=ldf(dt_bias,t,isbf); stb[t]=ldf(tt_bias,t,isbf);
        s1g[t]=ldf(ln1g,t,isbf); s1b[t]=ldf(ln1b,t,isbf);
        s2g[t]=ldf(ln2g,t,isbf); s2b[t]=ldf(ln2b,t,isbf);
        sptr[t]=ptrg[t];
    }
    if (t==0) s_nonuni = 0;
    __syncthreads();
    long i = blockIdx.x*256 + t;
    const float4* xp = (const float4*)(xt + i*16);
    float4 x0=xp[0], x1=xp[1], x2=xp[2], x3=xp[3];
    float vals[48];
    float* xv   = vals;
    float* tupd = vals+16;
    float* dupd = vals+32;
    xv[0]=x0.x; xv[1]=x0.y; xv[2]=x0.z; xv[3]=x0.w;
    xv[4]=x1.x; xv[5]=x1.y; xv[6]=x1.z; xv[7]=x1.w;
    xv[8]=x2.x; xv[9]=x2.y; xv[10]=x2.z; xv[11]=x2.w;
    xv[12]=x3.x; xv[13]=x3.y; xv[14]=x3.z; xv[15]=x3.w;
    {
        const float* ag = agg_dt + i*16;
        float v[16];
        #pragma unroll
        for (int c=0;c<16;c++){
            float r = sdb[c];
            #pragma unroll
            for (int k=0;k<16;k++) r += xv[k]*sdt[k*16+c];
            v[c] = fin(ag[c] + r);
        }
        ln_act16(v, s1g, s1b, dupd);
    }
    {
        const float* ag = agg_tt + i*16;
        float v[16];
        #pragma unroll
        for (int c=0;c<16;c++){
            float r = stb[c];
            #pragma unroll
            for (int k=0;k<16;k++) r += xv[k]*stt[k*16+c];
            v[c] = fin(ag[c] + r);
        }
        ln_act16(v, s2g, s2b, tupd);
    }
    #pragma unroll
    for (int j=0;j<48;j++) vals[j] = fin(vals[j]);
    #pragma unroll
    for (int g=0; g<16; g++){
        if (i == sptr[g]){
            for (int j=0;j<48;j++) stf(out, g*96+j, vals[j], isbf);
        }
    }
    int gi = b_tasks[i];
    int g0 = b_tasks[blockIdx.x*256];
    if (gi != g0) s_nonuni = 1;
    __syncthreads();
    if (s_nonuni){
        for (int j=0;j<48;j++) atomicAdd(&pool_sums[gi*48+j], vals[j]);
        atomicAdd(&pool_cnt[gi], 1.f);
    } else {
        int lane = t & 63, wid = t >> 6;
        #pragma unroll
        for (int j=0;j<48;j++){
            float v = vals[j];
            v += __shfl_down(v, 32);
            v += __shfl_down(v, 16);
            v += __shfl_down(v, 8);
            v += __shfl_down(v, 4);
            v += __shfl_down(v, 2);
            v += __shfl_down(v, 1);
            if (lane==0) swave[wid*48+j] = v;
        }
        __syncthreads();
        if (t < 48){
            float s = swave[t] + swave[48+t] + swave[96+t] + swave[144+t];
            atomicAdd(&pool_sums[g0*48+t], s);
        }
        if (t == 0) atomicAdd(&pool_cnt[g0], 256.f);
    }
    // last-block-done: final block computes the 768 pooled means
    __syncthreads();
    if (t == 0){
        __threadfence();
        s_last = (atomicAdd(done, 1) == gridDim.x - 1) ? 1 : 0;
    }
    __syncthreads();
    if (s_last){
        __threadfence();
        for (int j = t; j < 768; j += 256){
            int g = j/48, c = j - g*48;
            stf(out, g*96+48+c, fin(pool_sums[g*48+c]/fmaxf(pool_cnt[g],1.f)), isbf);
        }
    }
}

extern "C" void kernel_launch(void* const* d_in, const int* in_sizes, int n_in,
                              void* d_out, int out_size, void* d_ws, size_t ws_size,
                              hipStream_t stream)
{
    const void* x_tasks  = d_in[0];
    const void* x_data   = d_in[1];
    const void* stem_t_W = d_in[2];
    const void* stem_t_b = d_in[3];
    const void* stem_d_W = d_in[4];
    const void* stem_d_b = d_in[5];
    const void* ln_t_g   = d_in[6];
    const void* ln_t_b   = d_in[7];
    const void* ln_d_g   = d_in[8];
    const void* ln_d_b   = d_in[9];
    const void* dt_Wl    = d_in[10];
    const void* dt_Wr    = d_in[11];
    const void* dt_att   = d_in[12];
    const void* dt_res   = d_in[13];
    const void* dt_bias  = d_in[14];
    const void* tt_Wl    = d_in[15];
    const void* tt_Wr    = d_in[16];
    const void* tt_att   = d_in[17];
    const void* tt_res   = d_in[18];
    const void* tt_bias  = d_in[19];
    const void* ln1_g    = d_in[20];
    const void* ln1_b    = d_in[21];
    const void* ln2_g    = d_in[22];
    const void* ln2_b    = d_in[23];
    const int*  ei_dt    = (const int*)d_in[24];
    const int*  mask_dt  = (const int*)d_in[25];
    const int*  ei_tt    = (const int*)d_in[26];
    const int*  b_tasks  = (const int*)d_in[27];
    const int*  ptrg     = (const int*)d_in[28];

    char* w = (char*)d_ws;
    const size_t MB = 1ull<<20;
    float*    xt        = (float*)(w);              // 16 MB  [NT,16] fp32
    unsigned* xl_dt     = (unsigned*)(w + 16*MB);   // 16 MB  [ND,16] bf16x2-packed
    unsigned* xl_tt     = (unsigned*)(w + 32*MB);   // 16 MB  [NT,16] bf16x2-packed
    float*    agg       = (float*)(w + 48*MB);      // 32 MB  [NSLOT,16] fp32
    unsigned* ebuf      = (unsigned*)(w + 80*MB);   // 12 MB (NBKT*BCAP) + slack
    int*      bktCur    = (int*)  (w + 93*MB);      // 4 KB
    float*    pool_sums = (float*)(w + 93*MB + 8192);
    float*    pool_cnt  = (float*)(w + 93*MB + 12288);
    int*      flag      = (int*)  (w + 93*MB + 16384);
    int*      done      = (int*)  (w + 93*MB + 16388);

    setup_kernel<<<1, 256, 0, stream>>>((const unsigned*)x_tasks, flag, bktCur,
                                        pool_sums, pool_cnt, done);

    // mega: scatter first (overlaps with stems backfilling behind it)
    mega_kernel<<<NBLK_MEGA, 256, 0, stream>>>(
        x_tasks, x_data, stem_t_W, stem_t_b, ln_t_g, ln_t_b,
        stem_d_W, stem_d_b, ln_d_g, ln_d_b, tt_Wl, dt_Wl,
        xt, xl_tt, xl_dt, ei_dt, mask_dt, ei_tt, bktCur, ebuf, flag);

    // per-bucket LDS CSR + head-serial aggregation (both graphs)
    bucket_aggregate_kernel<<<NBKT, 256, 0, stream>>>(bktCur, ebuf, xt, xl_dt, xl_tt,
        dt_Wr, tt_Wr, dt_att, tt_att, agg, flag);

    // fuse + pool + output (finish folded in via last-block-done)
    fuse_pool_kernel<<<NT/256, 256, 0, stream>>>(xt, agg, agg + (long)NT*16,
        dt_res, dt_bias, tt_res, tt_bias, ln1_g, ln1_b, ln2_g, ln2_b,
        b_tasks, ptrg, pool_sums, pool_cnt, done, d_out, flag);
}